// Round 6
// baseline (423.795 us; speedup 1.0000x reference)
//
#include <hip/hip_runtime.h>

#define N_NODES 100000
#define N_EDGES 3200000
#define F_IN    128
#define HC      32      // H*C
#define CH      16      // C per head
#define NGRAPH  64
#define NEG     0.2f

#define BSH   8                                   // 256 nodes per bucket
#define BNODE (1 << BSH)
#define NB2   ((N_NODES + BNODE - 1) >> BSH)      // 391 buckets
#define CAP   9216                                // fixed staged slot per bucket (mean 8184 + 11 sigma)
#define EPB2  8192                                // edges per k_bucket block
#define BTHR  1024                                // k_bucket threads
#define HEPB  4096                                // edges per LDS-reorder half-pass
#define GPAD  16                                  // gcur stride (1 line/bucket)
#define SRCMID (N_NODES / 2)                      // src class boundary (phase-partitioned gather)

__device__ __forceinline__ float lrelu(float x) { return x > 0.f ? x : NEG * x; }

// ---------- init: fixed bucket bases + params zero ----------

__global__ void k_init(int* __restrict__ gcur, float* __restrict__ params) {
    int t = threadIdx.x;
    if (t < NB2) gcur[t * GPAD] = t * CAP;
    if (t < 16) params[t] = 0.f;
}

// ---------- pass A: bucket scatter with LDS reorder for coalesced staged stores ----------

__global__ __launch_bounds__(1024)
void k_bucket(const int* __restrict__ src, const int* __restrict__ dst,
              const float* __restrict__ ea, int* __restrict__ gcur,
              int2* __restrict__ staged, float* __restrict__ params) {
    __shared__ int lcur[NB2];
    __shared__ int lscan[512];
    __shared__ int gbase[NB2];
    __shared__ short rbkt[HEPB];
    __shared__ int2 recs[HEPB];
    int t = threadIdx.x;
    float acc = 0.f;
    for (int half = 0; half < 2; ++half) {
        int base = blockIdx.x * EPB2 + half * HEPB;
        for (int i = t; i < NB2; i += BTHR) lcur[i] = 0;
        __syncthreads();
        int  myb[HEPB / BTHR];
        int  myrank[HEPB / BTHR];
        int2 myrec[HEPB / BTHR];
#pragma unroll
        for (int i = 0; i < HEPB / BTHR; ++i) {
            int e = base + i * BTHR + t;
            myb[i] = -1;
            if (e < N_EDGES) {
                int dv = dst[e];
                float eav = ea[e];
                acc += eav;
                myb[i] = dv >> BSH;
                myrank[i] = atomicAdd(&lcur[myb[i]], 1);
                myrec[i] = make_int2((src[e] << BSH) | (dv & (BNODE - 1)),
                                     __float_as_int(eav));
            }
        }
        __syncthreads();
        if (t < 512) lscan[t] = (t < NB2) ? lcur[t] : 0;
        __syncthreads();
        for (int off = 1; off < 512; off <<= 1) {
            int u = 0;
            if (t < 512 && t >= off) u = lscan[t - off];
            __syncthreads();
            if (t < 512) lscan[t] += u;
            __syncthreads();
        }
        if (t < NB2 && lcur[t] > 0) gbase[t] = atomicAdd(&gcur[t * GPAD], lcur[t]);
        __syncthreads();
#pragma unroll
        for (int i = 0; i < HEPB / BTHR; ++i) {
            if (myb[i] >= 0) {
                int p = lscan[myb[i]] - lcur[myb[i]] + myrank[i];
                recs[p] = myrec[i];
                rbkt[p] = (short)myb[i];
            }
        }
        __syncthreads();
        int tot = lscan[511];
        for (int p = t; p < tot; p += BTHR) {
            int b = rbkt[p];
            int ex = lscan[b] - lcur[b];
            staged[gbase[b] + (p - ex)] = recs[p];
        }
        __syncthreads();
    }
    for (int m = 32; m >= 1; m >>= 1) acc += __shfl_xor(acc, m, 64);
    __shared__ float sh[BTHR / 64];
    int lane = t & 63, wid = t >> 6;
    if (lane == 0) sh[wid] = acc;
    __syncthreads();
    if (t == 0) {
        float s = 0.f;
        for (int i = 0; i < BTHR / 64; ++i) s += sh[i];
        unsafeAtomicAdd(&params[0], s);
    }
}

// ---------- params precompute + true bucket prefix scan (after binning) ----------

__global__ void k_setup(const float* __restrict__ We1, const float* __restrict__ ae1,
                        const float* __restrict__ We2, const float* __restrict__ ae2,
                        float* __restrict__ params, const int* __restrict__ gcur,
                        int* __restrict__ gstart, int* __restrict__ rowptr) {
    int t = threadIdx.x;
    if (t < 2) {
        float c1 = 0.f, c2 = 0.f;
        for (int c = 0; c < CH; ++c) {
            c1 += We1[t * CH + c] * ae1[t * CH + c];
            c2 += We2[t * CH + c] * ae2[t * CH + c];
        }
        params[2 + t] = c1;
        params[4 + t] = c2;
        if (t == 0) params[1] = params[0] / (float)N_EDGES;
    }
    __shared__ int sh[256];
    int v[2];
    int s = 0;
    for (int j = 0; j < 2; ++j) {
        int i = t * 2 + j;
        v[j] = (i < NB2) ? (gcur[i * GPAD] - i * CAP) : 0;
        s += v[j];
    }
    sh[t] = s;
    __syncthreads();
    for (int off = 1; off < 256; off <<= 1) {
        int u = (t >= off) ? sh[t - off] : 0;
        __syncthreads();
        sh[t] += u;
        __syncthreads();
    }
    int ex = sh[t] - s;
    for (int j = 0; j < 2; ++j) {
        int i = t * 2 + j;
        if (i < NB2) { gstart[i] = ex; ex += v[j]; }
    }
    if (t == 255) {
        gstart[NB2] = N_EDGES;
        rowptr[N_NODES] = N_EDGES;
    }
}

// ---------- pass B: per-bucket hist+scan, write rowptr/midp + class-split epack ----------
// Each node's run is [class-A (src<SRCMID) | class-B]. midp[n] = boundary.
// k_gat processes A then B, so the concurrent gather working set is halved.

__global__ void k_scatter(const int2* __restrict__ staged, const int* __restrict__ gcur,
                          const int* __restrict__ gstart,
                          int* __restrict__ rowptr, int* __restrict__ midp,
                          int2* __restrict__ epack) {
    __shared__ int cntl[BNODE];
    __shared__ int cntA[BNODE];
    __shared__ int scanb[BNODE];
    __shared__ int curA[BNODE];
    __shared__ int curB[BNODE];
    int b = blockIdx.x, t = threadIdx.x;
    int nbase = b << BSH;
    int bcount = N_NODES - nbase;
    if (bcount > BNODE) bcount = BNODE;
    int sbase = b * CAP;
    int en = gcur[b * GPAD];
    int st_true = gstart[b];
    if (t < BNODE) { cntl[t] = 0; cntA[t] = 0; }
    __syncthreads();
    for (int e = sbase + t; e < en; e += 1024) {
        int rx = staged[e].x;
        int lo = rx & (BNODE - 1);
        atomicAdd(&cntl[lo], 1);
        if ((rx >> BSH) < SRCMID) atomicAdd(&cntA[lo], 1);
    }
    __syncthreads();
    if (t < BNODE) scanb[t] = cntl[t];
    __syncthreads();
    for (int off = 1; off < BNODE; off <<= 1) {
        int u = (t < BNODE && t >= off) ? scanb[t - off] : 0;
        __syncthreads();
        if (t < BNODE) scanb[t] += u;
        __syncthreads();
    }
    if (t < BNODE) {
        int ex = st_true + scanb[t] - cntl[t];   // exclusive, global
        curA[t] = ex;
        curB[t] = ex + cntA[t];
        if (t < bcount) {
            rowptr[nbase + t] = ex;
            midp[nbase + t] = ex + cntA[t];
        }
    }
    __syncthreads();
    for (int e = sbase + t; e < en; e += 1024) {
        int2 r = staged[e];
        int lo = r.x & (BNODE - 1);
        int pos = ((r.x >> BSH) < SRCMID) ? atomicAdd(&curA[lo], 1)
                                          : atomicAdd(&curB[lo], 1);
        epack[pos] = r;
    }
}

// ---------- dense: h = x @ W (LDS-tiled), plus fused asrc/adst ----------

#define COLS(ac, xv)                                                     \
    ac[0] = fmaf(xv.x, w0.x, ac[0]); ac[1] = fmaf(xv.x, w0.y, ac[1]);    \
    ac[2] = fmaf(xv.x, w0.z, ac[2]); ac[3] = fmaf(xv.x, w0.w, ac[3]);    \
    ac[0] = fmaf(xv.y, w1.x, ac[0]); ac[1] = fmaf(xv.y, w1.y, ac[1]);    \
    ac[2] = fmaf(xv.y, w1.z, ac[2]); ac[3] = fmaf(xv.y, w1.w, ac[3]);    \
    ac[0] = fmaf(xv.z, w2.x, ac[0]); ac[1] = fmaf(xv.z, w2.y, ac[1]);    \
    ac[2] = fmaf(xv.z, w2.z, ac[2]); ac[3] = fmaf(xv.z, w2.w, ac[3]);    \
    ac[0] = fmaf(xv.w, w3.x, ac[0]); ac[1] = fmaf(xv.w, w3.y, ac[1]);    \
    ac[2] = fmaf(xv.w, w3.z, ac[2]); ac[3] = fmaf(xv.w, w3.w, ac[3]);

template <int FIN>
__global__ __launch_bounds__(256)
void k_linear(const float* __restrict__ x, const float* __restrict__ W,
              const float* __restrict__ a_src, const float* __restrict__ a_dst,
              float* __restrict__ h, float* __restrict__ asrc,
              float* __restrict__ adst) {
    constexpr int PAD = FIN + 4;
    __shared__ float ws[FIN * HC];
    __shared__ float xs[64 * PAD];
    int t = threadIdx.x;
    int nbase = blockIdx.x * 64;
    int bcount = N_NODES - nbase;
    if (bcount > 64) bcount = 64;

    for (int i = t; i < FIN * HC / 4; i += 256)
        ((float4*)ws)[i] = ((const float4*)W)[i];
    const float4* xg = (const float4*)(x + (size_t)nbase * FIN);
    int nf4 = bcount * FIN / 4;
    for (int i = t; i < 64 * FIN / 4; i += 256) {
        if (i < nf4) {
            float4 v = xg[i];
            int flat = i * 4;
            int row = flat / FIN, col = flat % FIN;
            *(float4*)&xs[row * PAD + col] = v;
        }
    }
    __syncthreads();

    int cg = t & 7, np = t >> 3;
    int n0 = np * 2, n1 = n0 + 1;
    float acc0[4] = {0.f, 0.f, 0.f, 0.f};
    float acc1[4] = {0.f, 0.f, 0.f, 0.f};
#pragma unroll
    for (int k = 0; k < FIN; k += 4) {
        float4 xa = *(const float4*)&xs[n0 * PAD + k];
        float4 xb = *(const float4*)&xs[n1 * PAD + k];
        const float4* wp = (const float4*)&ws[k * HC] + cg;
        float4 w0 = wp[0], w1 = wp[8], w2 = wp[16], w3 = wp[24];
        COLS(acc0, xa)
        COLS(acc1, xb)
    }

    int hh = cg >> 2;
    float s0 = 0.f, d0 = 0.f, s1 = 0.f, d1 = 0.f;
#pragma unroll
    for (int j = 0; j < 4; ++j) {
        float av = a_src[hh * CH + (cg & 3) * 4 + j];
        float dv = a_dst[hh * CH + (cg & 3) * 4 + j];
        s0 = fmaf(acc0[j], av, s0); d0 = fmaf(acc0[j], dv, d0);
        s1 = fmaf(acc1[j], av, s1); d1 = fmaf(acc1[j], dv, d1);
    }
    s0 += __shfl_xor(s0, 1, 64); s0 += __shfl_xor(s0, 2, 64);
    d0 += __shfl_xor(d0, 1, 64); d0 += __shfl_xor(d0, 2, 64);
    s1 += __shfl_xor(s1, 1, 64); s1 += __shfl_xor(s1, 2, 64);
    d1 += __shfl_xor(d1, 1, 64); d1 += __shfl_xor(d1, 2, 64);

    if (n0 < bcount) {
        *(float4*)&h[(size_t)(nbase + n0) * HC + cg * 4] =
            make_float4(acc0[0], acc0[1], acc0[2], acc0[3]);
        if ((cg & 3) == 0) {
            asrc[(nbase + n0) * 2 + hh] = s0;
            adst[(nbase + n0) * 2 + hh] = d0;
        }
    }
    if (n1 < bcount) {
        *(float4*)&h[(size_t)(nbase + n1) * HC + cg * 4] =
            make_float4(acc1[0], acc1[1], acc1[2], acc1[3]);
        if ((cg & 3) == 0) {
            asrc[(nbase + n1) * 2 + hh] = s1;
            adst[(nbase + n1) * 2 + hh] = d1;
        }
    }
}

// ---------- fused GAT layer: 16 lanes/node, class-A edges then class-B ----------

#define FMA4(ACC, WGT, VEC)                                                      \
    ACC.x = fmaf(WGT, VEC.x, ACC.x); ACC.y = fmaf(WGT, VEC.y, ACC.y);            \
    ACC.z = fmaf(WGT, VEC.z, ACC.z); ACC.w = fmaf(WGT, VEC.w, ACC.w);

#define GATLOOP(Q0, Q1)                                                            \
    for (int e = (Q0); e < (Q1); e += 4) {                                         \
        int e1 = e + 1, e2 = e + 2, e3 = e + 3;                                    \
        int i1 = e1 < (Q1) ? e1 : (Q1) - 1;                                        \
        int i2 = e2 < (Q1) ? e2 : (Q1) - 1;                                        \
        int i3 = e3 < (Q1) ? e3 : (Q1) - 1;                                        \
        int2 r0 = epack[e], r1 = epack[i1], r2 = epack[i2], r3 = epack[i3];        \
        int s0 = r0.x >> BSH, s1 = r1.x >> BSH, s2 = r2.x >> BSH, s3 = r3.x >> BSH;\
        float a0 = asrc[s0 * 2 + hh], a1 = asrc[s1 * 2 + hh];                      \
        float a2 = asrc[s2 * 2 + hh], a3 = asrc[s3 * 2 + hh];                      \
        float4 p0 = h4[s0 * 8 + b4], u0 = h4[s0 * 8 + b4 + 1];                     \
        float4 p1 = h4[s1 * 8 + b4], u1 = h4[s1 * 8 + b4 + 1];                     \
        float4 p2 = h4[s2 * 8 + b4], u2 = h4[s2 * 8 + b4 + 1];                     \
        float4 p3 = h4[s3 * 8 + b4], u3 = h4[s3 * 8 + b4 + 1];                     \
        float g0 = __expf(lrelu(a0 + adn + ce * __int_as_float(r0.y)));            \
        float g1 = __expf(lrelu(a1 + adn + ce * __int_as_float(r1.y)));            \
        float g2 = __expf(lrelu(a2 + adn + ce * __int_as_float(r2.y)));            \
        float g3 = __expf(lrelu(a3 + adn + ce * __int_as_float(r3.y)));            \
        g1 = (e1 < (Q1)) ? g1 : 0.f;                                               \
        g2 = (e2 < (Q1)) ? g2 : 0.f;                                               \
        g3 = (e3 < (Q1)) ? g3 : 0.f;                                               \
        FMA4(A0, g0, p0) FMA4(A1, g0, u0) ssum += g0;                              \
        FMA4(A0, g1, p1) FMA4(A1, g1, u1) ssum += g1;                              \
        FMA4(A0, g2, p2) FMA4(A1, g2, u2) ssum += g2;                              \
        FMA4(A0, g3, p3) FMA4(A1, g3, u3) ssum += g3;                              \
    }

__global__ __launch_bounds__(256)
void k_gat(const int* __restrict__ rowptr, const int* __restrict__ midp,
           const int2* __restrict__ epack, const float* __restrict__ h,
           const float* __restrict__ asrc, const float* __restrict__ adst,
           const float* __restrict__ params, int ceoff,
           const float* __restrict__ bias, int do_relu,
           float* __restrict__ out) {
    int tid = blockIdx.x * blockDim.x + threadIdx.x;
    int n = tid >> 4;
    if (n >= N_NODES) return;
    int q = tid & 15;
    int chan = q & 3, quarter = q >> 2, hh = chan >> 1;
    int b4 = chan * 2;                    // float4 index within 8-wide row
    int st = rowptr[n], en = rowptr[n + 1], mid = midp[n];
    float ce = params[ceoff + hh];
    float adn = adst[n * 2 + hh];
    const float4* h4 = (const float4*)h;
    float4 A0 = make_float4(0.f, 0.f, 0.f, 0.f);
    float4 A1 = make_float4(0.f, 0.f, 0.f, 0.f);
    float ssum = 0.f;
    // phase A: src < SRCMID (gather working set = lower half of h)
    int lenA = mid - st;
    int a0r = st + ((lenA * quarter) >> 2);
    int a1r = st + ((lenA * (quarter + 1)) >> 2);
    GATLOOP(a0r, a1r)
    // phase B: src >= SRCMID
    int lenB = en - mid;
    int b0r = mid + ((lenB * quarter) >> 2);
    int b1r = mid + ((lenB * (quarter + 1)) >> 2);
    GATLOOP(b0r, b1r)
    if (quarter == 0) {
        float gself = __expf(lrelu(asrc[n * 2 + hh] + adn + ce * params[1]));
        float4 psf = h4[n * 8 + b4], usf = h4[n * 8 + b4 + 1];
        FMA4(A0, gself, psf) FMA4(A1, gself, usf)
        ssum += gself;
    }
    // merge the four edge-quarters: partner lanes tid^4 then tid^8 (same wave)
    A0.x += __shfl_xor(A0.x, 4, 64); A0.y += __shfl_xor(A0.y, 4, 64);
    A0.z += __shfl_xor(A0.z, 4, 64); A0.w += __shfl_xor(A0.w, 4, 64);
    A1.x += __shfl_xor(A1.x, 4, 64); A1.y += __shfl_xor(A1.y, 4, 64);
    A1.z += __shfl_xor(A1.z, 4, 64); A1.w += __shfl_xor(A1.w, 4, 64);
    ssum += __shfl_xor(ssum, 4, 64);
    A0.x += __shfl_xor(A0.x, 8, 64); A0.y += __shfl_xor(A0.y, 8, 64);
    A0.z += __shfl_xor(A0.z, 8, 64); A0.w += __shfl_xor(A0.w, 8, 64);
    A1.x += __shfl_xor(A1.x, 8, 64); A1.y += __shfl_xor(A1.y, 8, 64);
    A1.z += __shfl_xor(A1.z, 8, 64); A1.w += __shfl_xor(A1.w, 8, 64);
    ssum += __shfl_xor(ssum, 8, 64);
    if (quarter != 0) return;
    float inv = 1.f / (ssum + 1e-16f);
    float4 bv0 = ((const float4*)bias)[b4], bv1 = ((const float4*)bias)[b4 + 1];
    float4 v0 = make_float4(A0.x * inv + bv0.x, A0.y * inv + bv0.y,
                            A0.z * inv + bv0.z, A0.w * inv + bv0.w);
    float4 v1 = make_float4(A1.x * inv + bv1.x, A1.y * inv + bv1.y,
                            A1.z * inv + bv1.z, A1.w * inv + bv1.w);
    if (do_relu) {
        v0.x = fmaxf(v0.x, 0.f); v0.y = fmaxf(v0.y, 0.f);
        v0.z = fmaxf(v0.z, 0.f); v0.w = fmaxf(v0.w, 0.f);
        v1.x = fmaxf(v1.x, 0.f); v1.y = fmaxf(v1.y, 0.f);
        v1.z = fmaxf(v1.z, 0.f); v1.w = fmaxf(v1.w, 0.f);
    }
    ((float4*)out)[n * 8 + b4] = v0;
    ((float4*)out)[n * 8 + b4 + 1] = v1;
}

// ---------- fused pooling (binary search on sorted batch) + MLP head ----------

__global__ void k_poolmlp(const float* __restrict__ feat, const int* __restrict__ batch,
                          const float* __restrict__ Wf1, const float* __restrict__ bf1,
                          const float* __restrict__ Wf2, const float* __restrict__ bf2,
                          float* __restrict__ out) {
    int g = blockIdx.x;
    __shared__ int sse[2];
    if (threadIdx.x < 2) {
        int target = g + (int)threadIdx.x;
        int lo = 0, hi = N_NODES;
        while (lo < hi) {
            int mid = (lo + hi) >> 1;
            if (batch[mid] < target) lo = mid + 1; else hi = mid;
        }
        sse[threadIdx.x] = lo;
    }
    __syncthreads();
    int st = sse[0], en = sse[1];
    int c = threadIdx.x & 31, r = threadIdx.x >> 5;  // r in 0..7
    float acc = 0.f;
    for (int n = st + r; n < en; n += 8) acc += feat[(size_t)n * HC + c];
    __shared__ float sh[8][32];
    sh[r][c] = acc;
    __syncthreads();
    __shared__ float emb[32];
    __shared__ float hid[32];
    if (threadIdx.x < 32) {
        float t = 0.f;
        for (int r2 = 0; r2 < 8; ++r2) t += sh[r2][c];
        int cnt = en - st;
        emb[c] = t / (float)(cnt > 0 ? cnt : 1);
    }
    __syncthreads();
    if (threadIdx.x < 32) {
        int j = threadIdx.x;
        float a = bf1[j];
        for (int k = 0; k < 32; ++k) a = fmaf(emb[k], Wf1[k * 32 + j], a);
        hid[j] = fmaxf(a, 0.f);
    }
    __syncthreads();
    if (threadIdx.x < 2) {
        int j = threadIdx.x;
        float o = bf2[j];
        for (int k = 0; k < 32; ++k) o = fmaf(hid[k], Wf2[k * 2 + j], o);
        out[g * 2 + j] = o;
    }
}

extern "C" void kernel_launch(void* const* d_in, const int* in_sizes, int n_in,
                              void* d_out, int out_size, void* d_ws, size_t ws_size,
                              hipStream_t stream) {
    const float* x   = (const float*)d_in[0];
    const int*   ei  = (const int*)d_in[1];
    const float* ea  = (const float*)d_in[2];
    const int* batch = (const int*)d_in[3];
    const float* W1  = (const float*)d_in[4];
    const float* as1 = (const float*)d_in[5];
    const float* ad1 = (const float*)d_in[6];
    const float* We1 = (const float*)d_in[7];
    const float* ae1 = (const float*)d_in[8];
    const float* b1  = (const float*)d_in[9];
    const float* W2  = (const float*)d_in[10];
    const float* as2 = (const float*)d_in[11];
    const float* ad2 = (const float*)d_in[12];
    const float* We2 = (const float*)d_in[13];
    const float* ae2 = (const float*)d_in[14];
    const float* b2  = (const float*)d_in[15];
    const float* Wf1 = (const float*)d_in[16];
    const float* bf1 = (const float*)d_in[17];
    const float* Wf2 = (const float*)d_in[18];
    const float* bf2 = (const float*)d_in[19];
    float* out = (float*)d_out;
    (void)in_sizes; (void)n_in; (void)out_size; (void)ws_size;

    const int* srcp = ei;
    const int* dstp = ei + N_EDGES;

    char* wsb = (char*)d_ws;
    size_t off = 0;
    auto alloc = [&](size_t bytes) -> char* {
        char* p = wsb + off;
        off = (off + bytes + 255) & ~(size_t)255;
        return p;
    };
    float* params = (float*)alloc(64);
    // region A: staged (NB2*CAP*8 = 28.8 MB), reused after k_scatter as hbuf + obuf
    char* regA = alloc((size_t)NB2 * CAP * 8 + 4096);
    int2*  staged = (int2*)regA;
    float* hbuf   = (float*)regA;
    float* obuf   = (float*)(regA + (size_t)N_NODES * HC * 4);
    int2*  epack  = (int2*)alloc((size_t)N_EDGES * 8);
    float* asrc   = (float*)alloc((size_t)N_NODES * 2 * 4);
    float* adst   = (float*)alloc((size_t)N_NODES * 2 * 4);
    int*   gstart = (int*)alloc((size_t)(NB2 + 1) * 4);
    int*   gcur   = (int*)alloc((size_t)NB2 * GPAD * 4);
    int*   rowptr = (int*)alloc((size_t)(N_NODES + 1) * 4);
    int*   midp   = (int*)alloc((size_t)N_NODES * 4);

    const int nBlkB = (N_EDGES + EPB2 - 1) / EPB2;              // 391
    const int nBlkL = (N_NODES + 63) / 64;                      // 1563
    const int nBlkG = (N_NODES * 16 + 255) / 256;               // 6250

    // fixed-capacity bucket sort (no pre-histogram pass)
    k_init<<<1, 512, 0, stream>>>(gcur, params);
    k_bucket<<<nBlkB, BTHR, 0, stream>>>(srcp, dstp, ea, gcur, staged, params);
    k_setup<<<1, 256, 0, stream>>>(We1, ae1, We2, ae2, params, gcur, gstart, rowptr);
    k_scatter<<<NB2, 1024, 0, stream>>>(staged, gcur, gstart, rowptr, midp, epack);

    // ----- layer 1 (hbuf/obuf overwrite staged region; stream-ordered, safe) -----
    k_linear<F_IN><<<nBlkL, 256, 0, stream>>>(x, W1, as1, ad1, hbuf, asrc, adst);
    k_gat<<<nBlkG, 256, 0, stream>>>(rowptr, midp, epack, hbuf, asrc, adst, params, 2, b1, 1, obuf);

    // ----- layer 2 -----
    k_linear<HC><<<nBlkL, 256, 0, stream>>>(obuf, W2, as2, ad2, hbuf, asrc, adst);
    k_gat<<<nBlkG, 256, 0, stream>>>(rowptr, midp, epack, hbuf, asrc, adst, params, 4, b2, 0, obuf);

    // ----- pool + MLP (fused; bounds via binary search on sorted batch) -----
    k_poolmlp<<<NGRAPH, 256, 0, stream>>>(obuf, batch, Wf1, bf1, Wf2, bf2, out);
}

// Round 7
// 363.814 us; speedup vs baseline: 1.1649x; 1.1649x over previous
//
#include <hip/hip_runtime.h>

#define N_NODES 100000
#define N_EDGES 3200000
#define F_IN    128
#define HC      32      // H*C
#define CH      16      // C per head
#define NGRAPH  64
#define NEG     0.2f

#define BSH   8                                   // 256 nodes per bucket
#define BNODE (1 << BSH)
#define NB2   ((N_NODES + BNODE - 1) >> BSH)      // 391 buckets
#define CAP   9216                                // fixed staged slot per bucket
#define EPB2  8192                                // edges per k_bucket block
#define BTHR  1024                                // k_bucket threads
#define HEPB  4096                                // edges per LDS-reorder half-pass
#define GPAD  16                                  // gcur stride (1 line/bucket)
#define CHK   4096                                // k_scatter chunk (LDS reorder)
#define NPB   512                                 // nodes per k_pool1 block
#define GSPAN 16                                  // max graphs spanned per pool block (LDS bins)

__device__ __forceinline__ float lrelu(float x) { return x > 0.f ? x : NEG * x; }

// ---------- init: fixed bucket bases + params + gsums zero ----------

__global__ void k_init(int* __restrict__ gcur, float* __restrict__ params,
                       float* __restrict__ gsums) {
    int t = threadIdx.x;
    if (t < NB2) gcur[t * GPAD] = t * CAP;
    if (t < 16) params[t] = 0.f;
    gsums[t] = 0.f;                 // 1024 threads
    gsums[t + 1024] = 0.f;          // total 2048 = NGRAPH*HC
}

// ---------- pass A: bucket scatter with LDS reorder for coalesced staged stores ----------

__global__ __launch_bounds__(1024)
void k_bucket(const int* __restrict__ src, const int* __restrict__ dst,
              const float* __restrict__ ea, int* __restrict__ gcur,
              int2* __restrict__ staged, float* __restrict__ params) {
    __shared__ int lcur[NB2];
    __shared__ int lscan[512];
    __shared__ int gbase[NB2];
    __shared__ short rbkt[HEPB];
    __shared__ int2 recs[HEPB];
    int t = threadIdx.x;
    float acc = 0.f;
    for (int half = 0; half < 2; ++half) {
        int base = blockIdx.x * EPB2 + half * HEPB;
        for (int i = t; i < NB2; i += BTHR) lcur[i] = 0;
        __syncthreads();
        int  myb[HEPB / BTHR];
        int  myrank[HEPB / BTHR];
        int2 myrec[HEPB / BTHR];
#pragma unroll
        for (int i = 0; i < HEPB / BTHR; ++i) {
            int e = base + i * BTHR + t;
            myb[i] = -1;
            if (e < N_EDGES) {
                int dv = dst[e];
                float eav = ea[e];
                acc += eav;
                myb[i] = dv >> BSH;
                myrank[i] = atomicAdd(&lcur[myb[i]], 1);
                myrec[i] = make_int2((src[e] << BSH) | (dv & (BNODE - 1)),
                                     __float_as_int(eav));
            }
        }
        __syncthreads();
        if (t < 512) lscan[t] = (t < NB2) ? lcur[t] : 0;
        __syncthreads();
        for (int off = 1; off < 512; off <<= 1) {
            int u = 0;
            if (t < 512 && t >= off) u = lscan[t - off];
            __syncthreads();
            if (t < 512) lscan[t] += u;
            __syncthreads();
        }
        if (t < NB2 && lcur[t] > 0) gbase[t] = atomicAdd(&gcur[t * GPAD], lcur[t]);
        __syncthreads();
#pragma unroll
        for (int i = 0; i < HEPB / BTHR; ++i) {
            if (myb[i] >= 0) {
                int p = lscan[myb[i]] - lcur[myb[i]] + myrank[i];
                recs[p] = myrec[i];
                rbkt[p] = (short)myb[i];
            }
        }
        __syncthreads();
        int tot = lscan[511];
        for (int p = t; p < tot; p += BTHR) {
            int b = rbkt[p];
            int ex = lscan[b] - lcur[b];
            staged[gbase[b] + (p - ex)] = recs[p];
        }
        __syncthreads();
    }
    for (int m = 32; m >= 1; m >>= 1) acc += __shfl_xor(acc, m, 64);
    __shared__ float sh[BTHR / 64];
    int lane = t & 63, wid = t >> 6;
    if (lane == 0) sh[wid] = acc;
    __syncthreads();
    if (t == 0) {
        float s = 0.f;
        for (int i = 0; i < BTHR / 64; ++i) s += sh[i];
        unsafeAtomicAdd(&params[0], s);
    }
}

// ---------- params precompute + bucket prefix scan ----------

__global__ void k_setup(const float* __restrict__ We1, const float* __restrict__ ae1,
                        const float* __restrict__ We2, const float* __restrict__ ae2,
                        float* __restrict__ params, const int* __restrict__ gcur,
                        int* __restrict__ gstart, int* __restrict__ rowptr) {
    int t = threadIdx.x;
    if (t < 2) {
        float c1 = 0.f, c2 = 0.f;
        for (int c = 0; c < CH; ++c) {
            c1 += We1[t * CH + c] * ae1[t * CH + c];
            c2 += We2[t * CH + c] * ae2[t * CH + c];
        }
        params[2 + t] = c1;
        params[4 + t] = c2;
        if (t == 0) params[1] = params[0] / (float)N_EDGES;
    }
    __shared__ int sh[256];
    int v[2];
    int s = 0;
    for (int j = 0; j < 2; ++j) {
        int i = t * 2 + j;
        v[j] = (i < NB2) ? (gcur[i * GPAD] - i * CAP) : 0;
        s += v[j];
    }
    sh[t] = s;
    __syncthreads();
    for (int off = 1; off < 256; off <<= 1) {
        int u = (t >= off) ? sh[t - off] : 0;
        __syncthreads();
        sh[t] += u;
        __syncthreads();
    }
    int ex = sh[t] - s;
    for (int j = 0; j < 2; ++j) {
        int i = t * 2 + j;
        if (i < NB2) { gstart[i] = ex; ex += v[j]; }
    }
    if (t == 255) {
        gstart[NB2] = N_EDGES;
        rowptr[N_NODES] = N_EDGES;
    }
}

// ---------- pass B: hist+scan, then CHUNKED LDS-reorder emission of epack ----------
// Chunks of 4096 edges are placed node-sorted in LDS, then emitted with
// consecutive lanes -> consecutive epack addresses (runs of ~32 edges/node).
// Replaces the random 8-B scatter (64 lines/wave) with ~2-4 lines/wave.

__global__ __launch_bounds__(1024)
void k_scatter(const int2* __restrict__ staged, const int* __restrict__ gcur,
               const int* __restrict__ gstart,
               int* __restrict__ rowptr, int2* __restrict__ epack) {
    __shared__ int cntl[BNODE];
    __shared__ int scanb[BNODE];
    __shared__ int cur[BNODE];
    __shared__ int cchist[BNODE];
    __shared__ int cexcl[BNODE];
    __shared__ short rbkt[CHK];
    __shared__ int2 recs[CHK];
    int b = blockIdx.x, t = threadIdx.x;
    int nbase = b << BSH;
    int bcount = N_NODES - nbase;
    if (bcount > BNODE) bcount = BNODE;
    int sbase = b * CAP;
    int en = gcur[b * GPAD];
    int st_true = gstart[b];
    if (t < BNODE) cntl[t] = 0;
    __syncthreads();
    for (int e = sbase + t; e < en; e += 1024)
        atomicAdd(&cntl[staged[e].x & (BNODE - 1)], 1);
    __syncthreads();
    if (t < BNODE) scanb[t] = cntl[t];
    __syncthreads();
    for (int off = 1; off < BNODE; off <<= 1) {
        int u = (t < BNODE && t >= off) ? scanb[t - off] : 0;
        __syncthreads();
        if (t < BNODE) scanb[t] += u;
        __syncthreads();
    }
    if (t < BNODE) {
        int ex = st_true + scanb[t] - cntl[t];   // exclusive, global
        cur[t] = ex;
        if (t < bcount) rowptr[nbase + t] = ex;
    }
    __syncthreads();
    int count = en - sbase;
    for (int cb = 0; cb < count; cb += CHK) {
        int clen = count - cb;
        if (clen > CHK) clen = CHK;
        if (t < BNODE) cchist[t] = 0;
        __syncthreads();
        int  mylo[CHK / 1024];
        int  myrank[CHK / 1024];
        int2 myrec[CHK / 1024];
#pragma unroll
        for (int i = 0; i < CHK / 1024; ++i) {
            int p = i * 1024 + t;
            mylo[i] = -1;
            if (p < clen) {
                int2 r = staged[sbase + cb + p];   // second read: L2-hot window
                mylo[i] = r.x & (BNODE - 1);
                myrank[i] = atomicAdd(&cchist[mylo[i]], 1);
                myrec[i] = r;
            }
        }
        __syncthreads();
        if (t < BNODE) cexcl[t] = cchist[t];
        __syncthreads();
        for (int off = 1; off < BNODE; off <<= 1) {
            int u = (t < BNODE && t >= off) ? cexcl[t - off] : 0;
            __syncthreads();
            if (t < BNODE) cexcl[t] += u;
            __syncthreads();
        }
        if (t < BNODE) cexcl[t] -= cchist[t];     // exclusive within chunk
        __syncthreads();
#pragma unroll
        for (int i = 0; i < CHK / 1024; ++i) {
            if (mylo[i] >= 0) {
                int p = cexcl[mylo[i]] + myrank[i];
                recs[p] = myrec[i];
                rbkt[p] = (short)mylo[i];
            }
        }
        __syncthreads();
        for (int p = t; p < clen; p += 1024) {
            int lo = rbkt[p];
            epack[cur[lo] + (p - cexcl[lo])] = recs[p];
        }
        __syncthreads();
        if (t < BNODE) cur[t] += cchist[t];
        __syncthreads();
    }
}

// ---------- dense: h = x @ W (LDS-tiled), plus fused asrc/adst ----------

#define COLS(ac, xv)                                                     \
    ac[0] = fmaf(xv.x, w0.x, ac[0]); ac[1] = fmaf(xv.x, w0.y, ac[1]);    \
    ac[2] = fmaf(xv.x, w0.z, ac[2]); ac[3] = fmaf(xv.x, w0.w, ac[3]);    \
    ac[0] = fmaf(xv.y, w1.x, ac[0]); ac[1] = fmaf(xv.y, w1.y, ac[1]);    \
    ac[2] = fmaf(xv.y, w1.z, ac[2]); ac[3] = fmaf(xv.y, w1.w, ac[3]);    \
    ac[0] = fmaf(xv.z, w2.x, ac[0]); ac[1] = fmaf(xv.z, w2.y, ac[1]);    \
    ac[2] = fmaf(xv.z, w2.z, ac[2]); ac[3] = fmaf(xv.z, w2.w, ac[3]);    \
    ac[0] = fmaf(xv.w, w3.x, ac[0]); ac[1] = fmaf(xv.w, w3.y, ac[1]);    \
    ac[2] = fmaf(xv.w, w3.z, ac[2]); ac[3] = fmaf(xv.w, w3.w, ac[3]);

template <int FIN>
__global__ __launch_bounds__(256)
void k_linear(const float* __restrict__ x, const float* __restrict__ W,
              const float* __restrict__ a_src, const float* __restrict__ a_dst,
              float* __restrict__ h, float* __restrict__ asrc,
              float* __restrict__ adst) {
    constexpr int PAD = FIN + 4;
    __shared__ float ws[FIN * HC];
    __shared__ float xs[64 * PAD];
    int t = threadIdx.x;
    int nbase = blockIdx.x * 64;
    int bcount = N_NODES - nbase;
    if (bcount > 64) bcount = 64;

    for (int i = t; i < FIN * HC / 4; i += 256)
        ((float4*)ws)[i] = ((const float4*)W)[i];
    const float4* xg = (const float4*)(x + (size_t)nbase * FIN);
    int nf4 = bcount * FIN / 4;
    for (int i = t; i < 64 * FIN / 4; i += 256) {
        if (i < nf4) {
            float4 v = xg[i];
            int flat = i * 4;
            int row = flat / FIN, col = flat % FIN;
            *(float4*)&xs[row * PAD + col] = v;
        }
    }
    __syncthreads();

    int cg = t & 7, np = t >> 3;
    int n0 = np * 2, n1 = n0 + 1;
    float acc0[4] = {0.f, 0.f, 0.f, 0.f};
    float acc1[4] = {0.f, 0.f, 0.f, 0.f};
#pragma unroll
    for (int k = 0; k < FIN; k += 4) {
        float4 xa = *(const float4*)&xs[n0 * PAD + k];
        float4 xb = *(const float4*)&xs[n1 * PAD + k];
        const float4* wp = (const float4*)&ws[k * HC] + cg;
        float4 w0 = wp[0], w1 = wp[8], w2 = wp[16], w3 = wp[24];
        COLS(acc0, xa)
        COLS(acc1, xb)
    }

    int hh = cg >> 2;
    float s0 = 0.f, d0 = 0.f, s1 = 0.f, d1 = 0.f;
#pragma unroll
    for (int j = 0; j < 4; ++j) {
        float av = a_src[hh * CH + (cg & 3) * 4 + j];
        float dv = a_dst[hh * CH + (cg & 3) * 4 + j];
        s0 = fmaf(acc0[j], av, s0); d0 = fmaf(acc0[j], dv, d0);
        s1 = fmaf(acc1[j], av, s1); d1 = fmaf(acc1[j], dv, d1);
    }
    s0 += __shfl_xor(s0, 1, 64); s0 += __shfl_xor(s0, 2, 64);
    d0 += __shfl_xor(d0, 1, 64); d0 += __shfl_xor(d0, 2, 64);
    s1 += __shfl_xor(s1, 1, 64); s1 += __shfl_xor(s1, 2, 64);
    d1 += __shfl_xor(d1, 1, 64); d1 += __shfl_xor(d1, 2, 64);

    if (n0 < bcount) {
        *(float4*)&h[(size_t)(nbase + n0) * HC + cg * 4] =
            make_float4(acc0[0], acc0[1], acc0[2], acc0[3]);
        if ((cg & 3) == 0) {
            asrc[(nbase + n0) * 2 + hh] = s0;
            adst[(nbase + n0) * 2 + hh] = d0;
        }
    }
    if (n1 < bcount) {
        *(float4*)&h[(size_t)(nbase + n1) * HC + cg * 4] =
            make_float4(acc1[0], acc1[1], acc1[2], acc1[3]);
        if ((cg & 3) == 0) {
            asrc[(nbase + n1) * 2 + hh] = s1;
            adst[(nbase + n1) * 2 + hh] = d1;
        }
    }
}

// ---------- fused GAT layer: 16 lanes/node = 4 channel-lanes x 4 edge-quarters ----------
// (R5 form: single range per node, clamped unroll-4, shfl merge 4 then 8)

#define FMA4(ACC, WGT, VEC)                                                      \
    ACC.x = fmaf(WGT, VEC.x, ACC.x); ACC.y = fmaf(WGT, VEC.y, ACC.y);            \
    ACC.z = fmaf(WGT, VEC.z, ACC.z); ACC.w = fmaf(WGT, VEC.w, ACC.w);

__global__ __launch_bounds__(256)
void k_gat(const int* __restrict__ rowptr, const int2* __restrict__ epack,
           const float* __restrict__ h,
           const float* __restrict__ asrc, const float* __restrict__ adst,
           const float* __restrict__ params, int ceoff,
           const float* __restrict__ bias, int do_relu,
           float* __restrict__ out) {
    int tid = blockIdx.x * blockDim.x + threadIdx.x;
    int n = tid >> 4;
    if (n >= N_NODES) return;
    int q = tid & 15;
    int chan = q & 3, quarter = q >> 2, hh = chan >> 1;
    int b4 = chan * 2;                    // float4 index within 8-wide row
    int st = rowptr[n], en = rowptr[n + 1];
    int len = en - st;
    int q0 = st + ((len * quarter) >> 2);
    int q1 = st + ((len * (quarter + 1)) >> 2);
    float ce = params[ceoff + hh];
    float adn = adst[n * 2 + hh];
    const float4* h4 = (const float4*)h;
    float4 A0 = make_float4(0.f, 0.f, 0.f, 0.f);
    float4 A1 = make_float4(0.f, 0.f, 0.f, 0.f);
    float ssum = 0.f;
    for (int e = q0; e < q1; e += 4) {
        int e1 = e + 1, e2 = e + 2, e3 = e + 3;
        int i1 = e1 < q1 ? e1 : q1 - 1;
        int i2 = e2 < q1 ? e2 : q1 - 1;
        int i3 = e3 < q1 ? e3 : q1 - 1;
        int2 r0 = epack[e], r1 = epack[i1], r2 = epack[i2], r3 = epack[i3];
        int s0 = r0.x >> BSH, s1 = r1.x >> BSH, s2 = r2.x >> BSH, s3 = r3.x >> BSH;
        float a0 = asrc[s0 * 2 + hh], a1 = asrc[s1 * 2 + hh];
        float a2 = asrc[s2 * 2 + hh], a3 = asrc[s3 * 2 + hh];
        float4 p0 = h4[s0 * 8 + b4], u0 = h4[s0 * 8 + b4 + 1];
        float4 p1 = h4[s1 * 8 + b4], u1 = h4[s1 * 8 + b4 + 1];
        float4 p2 = h4[s2 * 8 + b4], u2 = h4[s2 * 8 + b4 + 1];
        float4 p3 = h4[s3 * 8 + b4], u3 = h4[s3 * 8 + b4 + 1];
        float g0 = __expf(lrelu(a0 + adn + ce * __int_as_float(r0.y)));
        float g1 = __expf(lrelu(a1 + adn + ce * __int_as_float(r1.y)));
        float g2 = __expf(lrelu(a2 + adn + ce * __int_as_float(r2.y)));
        float g3 = __expf(lrelu(a3 + adn + ce * __int_as_float(r3.y)));
        g1 = (e1 < q1) ? g1 : 0.f;
        g2 = (e2 < q1) ? g2 : 0.f;
        g3 = (e3 < q1) ? g3 : 0.f;
        FMA4(A0, g0, p0) FMA4(A1, g0, u0) ssum += g0;
        FMA4(A0, g1, p1) FMA4(A1, g1, u1) ssum += g1;
        FMA4(A0, g2, p2) FMA4(A1, g2, u2) ssum += g2;
        FMA4(A0, g3, p3) FMA4(A1, g3, u3) ssum += g3;
    }
    if (quarter == 0) {
        // self-loop (eattr = mean) counted once, in quarter 0
        float gself = __expf(lrelu(asrc[n * 2 + hh] + adn + ce * params[1]));
        float4 psf = h4[n * 8 + b4], usf = h4[n * 8 + b4 + 1];
        FMA4(A0, gself, psf) FMA4(A1, gself, usf)
        ssum += gself;
    }
    // merge the four edge-quarters: partner lanes tid^4 then tid^8 (same wave)
    A0.x += __shfl_xor(A0.x, 4, 64); A0.y += __shfl_xor(A0.y, 4, 64);
    A0.z += __shfl_xor(A0.z, 4, 64); A0.w += __shfl_xor(A0.w, 4, 64);
    A1.x += __shfl_xor(A1.x, 4, 64); A1.y += __shfl_xor(A1.y, 4, 64);
    A1.z += __shfl_xor(A1.z, 4, 64); A1.w += __shfl_xor(A1.w, 4, 64);
    ssum += __shfl_xor(ssum, 4, 64);
    A0.x += __shfl_xor(A0.x, 8, 64); A0.y += __shfl_xor(A0.y, 8, 64);
    A0.z += __shfl_xor(A0.z, 8, 64); A0.w += __shfl_xor(A0.w, 8, 64);
    A1.x += __shfl_xor(A1.x, 8, 64); A1.y += __shfl_xor(A1.y, 8, 64);
    A1.z += __shfl_xor(A1.z, 8, 64); A1.w += __shfl_xor(A1.w, 8, 64);
    ssum += __shfl_xor(ssum, 8, 64);
    if (quarter != 0) return;
    float inv = 1.f / (ssum + 1e-16f);
    float4 bv0 = ((const float4*)bias)[b4], bv1 = ((const float4*)bias)[b4 + 1];
    float4 v0 = make_float4(A0.x * inv + bv0.x, A0.y * inv + bv0.y,
                            A0.z * inv + bv0.z, A0.w * inv + bv0.w);
    float4 v1 = make_float4(A1.x * inv + bv1.x, A1.y * inv + bv1.y,
                            A1.z * inv + bv1.z, A1.w * inv + bv1.w);
    if (do_relu) {
        v0.x = fmaxf(v0.x, 0.f); v0.y = fmaxf(v0.y, 0.f);
        v0.z = fmaxf(v0.z, 0.f); v0.w = fmaxf(v0.w, 0.f);
        v1.x = fmaxf(v1.x, 0.f); v1.y = fmaxf(v1.y, 0.f);
        v1.w = fmaxf(v1.w, 0.f); v1.z = fmaxf(v1.z, 0.f);
    }
    ((float4*)out)[n * 8 + b4] = v0;
    ((float4*)out)[n * 8 + b4 + 1] = v1;
}

// ---------- pooling stage 1: streaming per-graph partial sums ----------
// Block b covers nodes [b*NPB, b*NPB+NPB) (contiguous, coalesced reads).
// Sorted batch => block spans few graphs; per-thread run-accumulate flushes
// to LDS bins (relative graph index), then few global float atomics.

__global__ __launch_bounds__(1024)
void k_pool1(const float* __restrict__ feat, const int* __restrict__ batch,
             float* __restrict__ gsums) {
    __shared__ float gsum[GSPAN][32];
    int t = threadIdx.x;
    int c = t & 31, r = t >> 5;     // r in 0..31, 16 nodes each
    int base = blockIdx.x * NPB;
    if (t < GSPAN * 32) ((float*)gsum)[t] = 0.f;
    __syncthreads();
    int g0 = batch[base];
    float acc = 0.f;
    int gprev = -1;
    for (int i = 0; i < NPB / 32; ++i) {
        int n = base + r * (NPB / 32) + i;
        if (n >= N_NODES) break;
        int g = batch[n] - g0;
        if (g != gprev) {
            if (gprev >= 0) {
                if (gprev < GSPAN) atomicAdd(&gsum[gprev][c], acc);
                else unsafeAtomicAdd(&gsums[(g0 + gprev) * 32 + c], acc);
            }
            acc = 0.f;
            gprev = g;
        }
        acc += feat[(size_t)n * HC + c];
    }
    if (gprev >= 0) {
        if (gprev < GSPAN) atomicAdd(&gsum[gprev][c], acc);
        else unsafeAtomicAdd(&gsums[(g0 + gprev) * 32 + c], acc);
    }
    __syncthreads();
    if (t < GSPAN * 32) {
        int gi = t >> 5, cc = t & 31;
        float v = gsum[gi][cc];
        if (v != 0.f && g0 + gi < NGRAPH)
            unsafeAtomicAdd(&gsums[(g0 + gi) * 32 + cc], v);
    }
}

// ---------- pooling stage 2: mean + MLP head (tiny) ----------

__global__ void k_mlp(const float* __restrict__ gsums, const int* __restrict__ batch,
                      const float* __restrict__ Wf1, const float* __restrict__ bf1,
                      const float* __restrict__ Wf2, const float* __restrict__ bf2,
                      float* __restrict__ out) {
    int g = blockIdx.x;
    __shared__ int sse[2];
    __shared__ float emb[32];
    __shared__ float hid[32];
    if (threadIdx.x < 2) {
        int target = g + (int)threadIdx.x;
        int lo = 0, hi = N_NODES;
        while (lo < hi) {
            int mid = (lo + hi) >> 1;
            if (batch[mid] < target) lo = mid + 1; else hi = mid;
        }
        sse[threadIdx.x] = lo;
    }
    __syncthreads();
    int cnt = sse[1] - sse[0];
    if (threadIdx.x < 32)
        emb[threadIdx.x] = gsums[g * 32 + threadIdx.x] / (float)(cnt > 0 ? cnt : 1);
    __syncthreads();
    if (threadIdx.x < 32) {
        int j = threadIdx.x;
        float a = bf1[j];
        for (int k = 0; k < 32; ++k) a = fmaf(emb[k], Wf1[k * 32 + j], a);
        hid[j] = fmaxf(a, 0.f);
    }
    __syncthreads();
    if (threadIdx.x < 2) {
        int j = threadIdx.x;
        float o = bf2[j];
        for (int k = 0; k < 32; ++k) o = fmaf(hid[k], Wf2[k * 2 + j], o);
        out[g * 2 + j] = o;
    }
}

extern "C" void kernel_launch(void* const* d_in, const int* in_sizes, int n_in,
                              void* d_out, int out_size, void* d_ws, size_t ws_size,
                              hipStream_t stream) {
    const float* x   = (const float*)d_in[0];
    const int*   ei  = (const int*)d_in[1];
    const float* ea  = (const float*)d_in[2];
    const int* batch = (const int*)d_in[3];
    const float* W1  = (const float*)d_in[4];
    const float* as1 = (const float*)d_in[5];
    const float* ad1 = (const float*)d_in[6];
    const float* We1 = (const float*)d_in[7];
    const float* ae1 = (const float*)d_in[8];
    const float* b1  = (const float*)d_in[9];
    const float* W2  = (const float*)d_in[10];
    const float* as2 = (const float*)d_in[11];
    const float* ad2 = (const float*)d_in[12];
    const float* We2 = (const float*)d_in[13];
    const float* ae2 = (const float*)d_in[14];
    const float* b2  = (const float*)d_in[15];
    const float* Wf1 = (const float*)d_in[16];
    const float* bf1 = (const float*)d_in[17];
    const float* Wf2 = (const float*)d_in[18];
    const float* bf2 = (const float*)d_in[19];
    float* out = (float*)d_out;
    (void)in_sizes; (void)n_in; (void)out_size; (void)ws_size;

    const int* srcp = ei;
    const int* dstp = ei + N_EDGES;

    char* wsb = (char*)d_ws;
    size_t off = 0;
    auto alloc = [&](size_t bytes) -> char* {
        char* p = wsb + off;
        off = (off + bytes + 255) & ~(size_t)255;
        return p;
    };
    float* params = (float*)alloc(64);
    // region A: staged (NB2*CAP*8 = 28.8 MB), reused after k_scatter as hbuf + obuf
    char* regA = alloc((size_t)NB2 * CAP * 8 + 4096);
    int2*  staged = (int2*)regA;
    float* hbuf   = (float*)regA;
    float* obuf   = (float*)(regA + (size_t)N_NODES * HC * 4);
    int2*  epack  = (int2*)alloc((size_t)N_EDGES * 8);
    float* asrc   = (float*)alloc((size_t)N_NODES * 2 * 4);
    float* adst   = (float*)alloc((size_t)N_NODES * 2 * 4);
    int*   gstart = (int*)alloc((size_t)(NB2 + 1) * 4);
    int*   gcur   = (int*)alloc((size_t)NB2 * GPAD * 4);
    int*   rowptr = (int*)alloc((size_t)(N_NODES + 1) * 4);
    float* gsums  = (float*)alloc((size_t)NGRAPH * HC * 4);

    const int nBlkB = (N_EDGES + EPB2 - 1) / EPB2;              // 391
    const int nBlkL = (N_NODES + 63) / 64;                      // 1563
    const int nBlkG = (N_NODES * 16 + 255) / 256;               // 6250
    const int nBlkP = (N_NODES + NPB - 1) / NPB;                // 196

    // fixed-capacity bucket sort (no pre-histogram pass)
    k_init<<<1, 1024, 0, stream>>>(gcur, params, gsums);
    k_bucket<<<nBlkB, BTHR, 0, stream>>>(srcp, dstp, ea, gcur, staged, params);
    k_setup<<<1, 256, 0, stream>>>(We1, ae1, We2, ae2, params, gcur, gstart, rowptr);
    k_scatter<<<NB2, 1024, 0, stream>>>(staged, gcur, gstart, rowptr, epack);

    // ----- layer 1 (hbuf/obuf overwrite staged region; stream-ordered, safe) -----
    k_linear<F_IN><<<nBlkL, 256, 0, stream>>>(x, W1, as1, ad1, hbuf, asrc, adst);
    k_gat<<<nBlkG, 256, 0, stream>>>(rowptr, epack, hbuf, asrc, adst, params, 2, b1, 1, obuf);

    // ----- layer 2 -----
    k_linear<HC><<<nBlkL, 256, 0, stream>>>(obuf, W2, as2, ad2, hbuf, asrc, adst);
    k_gat<<<nBlkG, 256, 0, stream>>>(rowptr, epack, hbuf, asrc, adst, params, 4, b2, 0, obuf);

    // ----- pool (streaming partials) + MLP head -----
    k_pool1<<<nBlkP, 1024, 0, stream>>>(obuf, batch, gsums);
    k_mlp<<<NGRAPH, 64, 0, stream>>>(gsums, batch, Wf1, bf1, Wf2, bf2, out);
}

// Round 8
// 351.295 us; speedup vs baseline: 1.2064x; 1.0356x over previous
//
#include <hip/hip_runtime.h>

#define N_NODES 100000
#define N_EDGES 3200000
#define F_IN    128
#define HC      32      // H*C
#define CH      16      // C per head
#define NGRAPH  64
#define NEG     0.2f

#define BSH   8                                   // 256 nodes per bucket
#define BNODE (1 << BSH)
#define NB2   ((N_NODES + BNODE - 1) >> BSH)      // 391 buckets
#define CAP   9216                                // fixed staged slot per bucket
#define EPB2  8192                                // edges per k_bucket block
#define BTHR  1024                                // k_bucket threads
#define HEPB  4096                                // edges per LDS-reorder half-pass
#define GPAD  16                                  // gcur stride (1 line/bucket)
#define CHK   4096                                // k_scatter chunk (LDS reorder)
#define NPB   512                                 // nodes per k_pool1 block
#define GSPAN 16                                  // max graphs spanned per pool block (LDS bins)

__device__ __forceinline__ float lrelu(float x) { return x > 0.f ? x : NEG * x; }

// ---------- init: fixed bucket bases + params + gsums zero ----------

__global__ void k_init(int* __restrict__ gcur, float* __restrict__ params,
                       float* __restrict__ gsums) {
    int t = threadIdx.x;
    if (t < NB2) gcur[t * GPAD] = t * CAP;
    if (t < 16) params[t] = 0.f;
    gsums[t] = 0.f;                 // 1024 threads
    gsums[t + 1024] = 0.f;          // total 2048 = NGRAPH*HC
}

// ---------- pass A: bucket scatter with LDS reorder for coalesced staged stores ----------

__global__ __launch_bounds__(1024)
void k_bucket(const int* __restrict__ src, const int* __restrict__ dst,
              const float* __restrict__ ea, int* __restrict__ gcur,
              int2* __restrict__ staged, float* __restrict__ params) {
    __shared__ int lcur[NB2];
    __shared__ int lscan[512];
    __shared__ int gbase[NB2];
    __shared__ short rbkt[HEPB];
    __shared__ int2 recs[HEPB];
    int t = threadIdx.x;
    float acc = 0.f;
    for (int half = 0; half < 2; ++half) {
        int base = blockIdx.x * EPB2 + half * HEPB;
        for (int i = t; i < NB2; i += BTHR) lcur[i] = 0;
        __syncthreads();
        int  myb[HEPB / BTHR];
        int  myrank[HEPB / BTHR];
        int2 myrec[HEPB / BTHR];
#pragma unroll
        for (int i = 0; i < HEPB / BTHR; ++i) {
            int e = base + i * BTHR + t;
            myb[i] = -1;
            if (e < N_EDGES) {
                int dv = dst[e];
                float eav = ea[e];
                acc += eav;
                myb[i] = dv >> BSH;
                myrank[i] = atomicAdd(&lcur[myb[i]], 1);
                myrec[i] = make_int2((src[e] << BSH) | (dv & (BNODE - 1)),
                                     __float_as_int(eav));
            }
        }
        __syncthreads();
        if (t < 512) lscan[t] = (t < NB2) ? lcur[t] : 0;
        __syncthreads();
        for (int off = 1; off < 512; off <<= 1) {
            int u = 0;
            if (t < 512 && t >= off) u = lscan[t - off];
            __syncthreads();
            if (t < 512) lscan[t] += u;
            __syncthreads();
        }
        if (t < NB2 && lcur[t] > 0) gbase[t] = atomicAdd(&gcur[t * GPAD], lcur[t]);
        __syncthreads();
#pragma unroll
        for (int i = 0; i < HEPB / BTHR; ++i) {
            if (myb[i] >= 0) {
                int p = lscan[myb[i]] - lcur[myb[i]] + myrank[i];
                recs[p] = myrec[i];
                rbkt[p] = (short)myb[i];
            }
        }
        __syncthreads();
        int tot = lscan[511];
        for (int p = t; p < tot; p += BTHR) {
            int b = rbkt[p];
            int ex = lscan[b] - lcur[b];
            staged[gbase[b] + (p - ex)] = recs[p];
        }
        __syncthreads();
    }
    for (int m = 32; m >= 1; m >>= 1) acc += __shfl_xor(acc, m, 64);
    __shared__ float sh[BTHR / 64];
    int lane = t & 63, wid = t >> 6;
    if (lane == 0) sh[wid] = acc;
    __syncthreads();
    if (t == 0) {
        float s = 0.f;
        for (int i = 0; i < BTHR / 64; ++i) s += sh[i];
        unsafeAtomicAdd(&params[0], s);
    }
}

// ---------- params precompute + bucket prefix scan ----------

__global__ void k_setup(const float* __restrict__ We1, const float* __restrict__ ae1,
                        const float* __restrict__ We2, const float* __restrict__ ae2,
                        float* __restrict__ params, const int* __restrict__ gcur,
                        int* __restrict__ gstart, int* __restrict__ rowptr) {
    int t = threadIdx.x;
    if (t < 2) {
        float c1 = 0.f, c2 = 0.f;
        for (int c = 0; c < CH; ++c) {
            c1 += We1[t * CH + c] * ae1[t * CH + c];
            c2 += We2[t * CH + c] * ae2[t * CH + c];
        }
        params[2 + t] = c1;
        params[4 + t] = c2;
        if (t == 0) params[1] = params[0] / (float)N_EDGES;
    }
    __shared__ int sh[256];
    int v[2];
    int s = 0;
    for (int j = 0; j < 2; ++j) {
        int i = t * 2 + j;
        v[j] = (i < NB2) ? (gcur[i * GPAD] - i * CAP) : 0;
        s += v[j];
    }
    sh[t] = s;
    __syncthreads();
    for (int off = 1; off < 256; off <<= 1) {
        int u = (t >= off) ? sh[t - off] : 0;
        __syncthreads();
        sh[t] += u;
        __syncthreads();
    }
    int ex = sh[t] - s;
    for (int j = 0; j < 2; ++j) {
        int i = t * 2 + j;
        if (i < NB2) { gstart[i] = ex; ex += v[j]; }
    }
    if (t == 255) {
        gstart[NB2] = N_EDGES;
        rowptr[N_NODES] = N_EDGES;
    }
}

// ---------- pass B: hist+scan, then CHUNKED LDS-reorder emission of epack ----------

__global__ __launch_bounds__(1024)
void k_scatter(const int2* __restrict__ staged, const int* __restrict__ gcur,
               const int* __restrict__ gstart,
               int* __restrict__ rowptr, int2* __restrict__ epack) {
    __shared__ int cntl[BNODE];
    __shared__ int scanb[BNODE];
    __shared__ int cur[BNODE];
    __shared__ int cchist[BNODE];
    __shared__ int cexcl[BNODE];
    __shared__ short rbkt[CHK];
    __shared__ int2 recs[CHK];
    int b = blockIdx.x, t = threadIdx.x;
    int nbase = b << BSH;
    int bcount = N_NODES - nbase;
    if (bcount > BNODE) bcount = BNODE;
    int sbase = b * CAP;
    int en = gcur[b * GPAD];
    int st_true = gstart[b];
    if (t < BNODE) cntl[t] = 0;
    __syncthreads();
    for (int e = sbase + t; e < en; e += 1024)
        atomicAdd(&cntl[staged[e].x & (BNODE - 1)], 1);
    __syncthreads();
    if (t < BNODE) scanb[t] = cntl[t];
    __syncthreads();
    for (int off = 1; off < BNODE; off <<= 1) {
        int u = (t < BNODE && t >= off) ? scanb[t - off] : 0;
        __syncthreads();
        if (t < BNODE) scanb[t] += u;
        __syncthreads();
    }
    if (t < BNODE) {
        int ex = st_true + scanb[t] - cntl[t];   // exclusive, global
        cur[t] = ex;
        if (t < bcount) rowptr[nbase + t] = ex;
    }
    __syncthreads();
    int count = en - sbase;
    for (int cb = 0; cb < count; cb += CHK) {
        int clen = count - cb;
        if (clen > CHK) clen = CHK;
        if (t < BNODE) cchist[t] = 0;
        __syncthreads();
        int  mylo[CHK / 1024];
        int  myrank[CHK / 1024];
        int2 myrec[CHK / 1024];
#pragma unroll
        for (int i = 0; i < CHK / 1024; ++i) {
            int p = i * 1024 + t;
            mylo[i] = -1;
            if (p < clen) {
                int2 r = staged[sbase + cb + p];   // second read: L2-hot window
                mylo[i] = r.x & (BNODE - 1);
                myrank[i] = atomicAdd(&cchist[mylo[i]], 1);
                myrec[i] = r;
            }
        }
        __syncthreads();
        if (t < BNODE) cexcl[t] = cchist[t];
        __syncthreads();
        for (int off = 1; off < BNODE; off <<= 1) {
            int u = (t < BNODE && t >= off) ? cexcl[t - off] : 0;
            __syncthreads();
            if (t < BNODE) cexcl[t] += u;
            __syncthreads();
        }
        if (t < BNODE) cexcl[t] -= cchist[t];     // exclusive within chunk
        __syncthreads();
#pragma unroll
        for (int i = 0; i < CHK / 1024; ++i) {
            if (mylo[i] >= 0) {
                int p = cexcl[mylo[i]] + myrank[i];
                recs[p] = myrec[i];
                rbkt[p] = (short)mylo[i];
            }
        }
        __syncthreads();
        for (int p = t; p < clen; p += 1024) {
            int lo = rbkt[p];
            epack[cur[lo] + (p - cexcl[lo])] = recs[p];
        }
        __syncthreads();
        if (t < BNODE) cur[t] += cchist[t];
        __syncthreads();
    }
}

// ---------- dense: h = x @ W (LDS-tiled), plus fused asrc/adst ----------

#define COLS(ac, xv)                                                     \
    ac[0] = fmaf(xv.x, w0.x, ac[0]); ac[1] = fmaf(xv.x, w0.y, ac[1]);    \
    ac[2] = fmaf(xv.x, w0.z, ac[2]); ac[3] = fmaf(xv.x, w0.w, ac[3]);    \
    ac[0] = fmaf(xv.y, w1.x, ac[0]); ac[1] = fmaf(xv.y, w1.y, ac[1]);    \
    ac[2] = fmaf(xv.y, w1.z, ac[2]); ac[3] = fmaf(xv.y, w1.w, ac[3]);    \
    ac[0] = fmaf(xv.z, w2.x, ac[0]); ac[1] = fmaf(xv.z, w2.y, ac[1]);    \
    ac[2] = fmaf(xv.z, w2.z, ac[2]); ac[3] = fmaf(xv.z, w2.w, ac[3]);    \
    ac[0] = fmaf(xv.w, w3.x, ac[0]); ac[1] = fmaf(xv.w, w3.y, ac[1]);    \
    ac[2] = fmaf(xv.w, w3.z, ac[2]); ac[3] = fmaf(xv.w, w3.w, ac[3]);

template <int FIN>
__global__ __launch_bounds__(256)
void k_linear(const float* __restrict__ x, const float* __restrict__ W,
              const float* __restrict__ a_src, const float* __restrict__ a_dst,
              float* __restrict__ h, float* __restrict__ asrc,
              float* __restrict__ adst) {
    constexpr int PAD = FIN + 4;
    __shared__ float ws[FIN * HC];
    __shared__ float xs[64 * PAD];
    int t = threadIdx.x;
    int nbase = blockIdx.x * 64;
    int bcount = N_NODES - nbase;
    if (bcount > 64) bcount = 64;

    for (int i = t; i < FIN * HC / 4; i += 256)
        ((float4*)ws)[i] = ((const float4*)W)[i];
    const float4* xg = (const float4*)(x + (size_t)nbase * FIN);
    int nf4 = bcount * FIN / 4;
    for (int i = t; i < 64 * FIN / 4; i += 256) {
        if (i < nf4) {
            float4 v = xg[i];
            int flat = i * 4;
            int row = flat / FIN, col = flat % FIN;
            *(float4*)&xs[row * PAD + col] = v;
        }
    }
    __syncthreads();

    int cg = t & 7, np = t >> 3;
    int n0 = np * 2, n1 = n0 + 1;
    float acc0[4] = {0.f, 0.f, 0.f, 0.f};
    float acc1[4] = {0.f, 0.f, 0.f, 0.f};
#pragma unroll
    for (int k = 0; k < FIN; k += 4) {
        float4 xa = *(const float4*)&xs[n0 * PAD + k];
        float4 xb = *(const float4*)&xs[n1 * PAD + k];
        const float4* wp = (const float4*)&ws[k * HC] + cg;
        float4 w0 = wp[0], w1 = wp[8], w2 = wp[16], w3 = wp[24];
        COLS(acc0, xa)
        COLS(acc1, xb)
    }

    int hh = cg >> 2;
    float s0 = 0.f, d0 = 0.f, s1 = 0.f, d1 = 0.f;
#pragma unroll
    for (int j = 0; j < 4; ++j) {
        float av = a_src[hh * CH + (cg & 3) * 4 + j];
        float dv = a_dst[hh * CH + (cg & 3) * 4 + j];
        s0 = fmaf(acc0[j], av, s0); d0 = fmaf(acc0[j], dv, d0);
        s1 = fmaf(acc1[j], av, s1); d1 = fmaf(acc1[j], dv, d1);
    }
    s0 += __shfl_xor(s0, 1, 64); s0 += __shfl_xor(s0, 2, 64);
    d0 += __shfl_xor(d0, 1, 64); d0 += __shfl_xor(d0, 2, 64);
    s1 += __shfl_xor(s1, 1, 64); s1 += __shfl_xor(s1, 2, 64);
    d1 += __shfl_xor(d1, 1, 64); d1 += __shfl_xor(d1, 2, 64);

    if (n0 < bcount) {
        *(float4*)&h[(size_t)(nbase + n0) * HC + cg * 4] =
            make_float4(acc0[0], acc0[1], acc0[2], acc0[3]);
        if ((cg & 3) == 0) {
            asrc[(nbase + n0) * 2 + hh] = s0;
            adst[(nbase + n0) * 2 + hh] = d0;
        }
    }
    if (n1 < bcount) {
        *(float4*)&h[(size_t)(nbase + n1) * HC + cg * 4] =
            make_float4(acc1[0], acc1[1], acc1[2], acc1[3]);
        if ((cg & 3) == 0) {
            asrc[(nbase + n1) * 2 + hh] = s1;
            adst[(nbase + n1) * 2 + hh] = d1;
        }
    }
}

// ---------- fused GAT layer: 16 lanes/node = 4 channel-lanes x 4 edge-quarters ----------
// fuse=1 (layer 1): epilogue additionally computes h2 = relu(out) @ W2 via
// in-wave shfl among the 4 chan lanes (k-ascending FMA order == k_linear's),
// plus asrc2/adst2 dot products. Eliminates the k_linear<HC> kernel; the
// matmul VALU hides under the gather latency (VALUBusy only ~25%).

#define FMA4(ACC, WGT, VEC)                                                      \
    ACC.x = fmaf(WGT, VEC.x, ACC.x); ACC.y = fmaf(WGT, VEC.y, ACC.y);            \
    ACC.z = fmaf(WGT, VEC.z, ACC.z); ACC.w = fmaf(WGT, VEC.w, ACC.w);

__global__ __launch_bounds__(256)
void k_gat(const int* __restrict__ rowptr, const int2* __restrict__ epack,
           const float* __restrict__ h,
           const float* __restrict__ asrc, const float* __restrict__ adst,
           const float* __restrict__ params, int ceoff,
           const float* __restrict__ bias, int do_relu,
           float* __restrict__ out,
           int fuse, const float* __restrict__ W2,
           const float* __restrict__ as2, const float* __restrict__ ad2,
           float* __restrict__ asrc2, float* __restrict__ adst2) {
    __shared__ float w2s[HC * HC];
    int t = threadIdx.x;
    if (fuse) {
        for (int i = t; i < HC * HC / 4; i += 256)
            ((float4*)w2s)[i] = ((const float4*)W2)[i];
        __syncthreads();
    }
    int tid = blockIdx.x * blockDim.x + t;
    int n = tid >> 4;
    if (n >= N_NODES) return;
    int q = tid & 15;
    int chan = q & 3, quarter = q >> 2, hh = chan >> 1;
    int b4 = chan * 2;                    // float4 index within 8-wide row
    int st = rowptr[n], en = rowptr[n + 1];
    int len = en - st;
    int q0 = st + ((len * quarter) >> 2);
    int q1 = st + ((len * (quarter + 1)) >> 2);
    float ce = params[ceoff + hh];
    float adn = adst[n * 2 + hh];
    const float4* h4 = (const float4*)h;
    float4 A0 = make_float4(0.f, 0.f, 0.f, 0.f);
    float4 A1 = make_float4(0.f, 0.f, 0.f, 0.f);
    float ssum = 0.f;
    for (int e = q0; e < q1; e += 4) {
        int e1 = e + 1, e2 = e + 2, e3 = e + 3;
        int i1 = e1 < q1 ? e1 : q1 - 1;
        int i2 = e2 < q1 ? e2 : q1 - 1;
        int i3 = e3 < q1 ? e3 : q1 - 1;
        int2 r0 = epack[e], r1 = epack[i1], r2 = epack[i2], r3 = epack[i3];
        int s0 = r0.x >> BSH, s1 = r1.x >> BSH, s2 = r2.x >> BSH, s3 = r3.x >> BSH;
        float a0 = asrc[s0 * 2 + hh], a1 = asrc[s1 * 2 + hh];
        float a2 = asrc[s2 * 2 + hh], a3 = asrc[s3 * 2 + hh];
        float4 p0 = h4[s0 * 8 + b4], u0 = h4[s0 * 8 + b4 + 1];
        float4 p1 = h4[s1 * 8 + b4], u1 = h4[s1 * 8 + b4 + 1];
        float4 p2 = h4[s2 * 8 + b4], u2 = h4[s2 * 8 + b4 + 1];
        float4 p3 = h4[s3 * 8 + b4], u3 = h4[s3 * 8 + b4 + 1];
        float g0 = __expf(lrelu(a0 + adn + ce * __int_as_float(r0.y)));
        float g1 = __expf(lrelu(a1 + adn + ce * __int_as_float(r1.y)));
        float g2 = __expf(lrelu(a2 + adn + ce * __int_as_float(r2.y)));
        float g3 = __expf(lrelu(a3 + adn + ce * __int_as_float(r3.y)));
        g1 = (e1 < q1) ? g1 : 0.f;
        g2 = (e2 < q1) ? g2 : 0.f;
        g3 = (e3 < q1) ? g3 : 0.f;
        FMA4(A0, g0, p0) FMA4(A1, g0, u0) ssum += g0;
        FMA4(A0, g1, p1) FMA4(A1, g1, u1) ssum += g1;
        FMA4(A0, g2, p2) FMA4(A1, g2, u2) ssum += g2;
        FMA4(A0, g3, p3) FMA4(A1, g3, u3) ssum += g3;
    }
    if (quarter == 0) {
        // self-loop (eattr = mean) counted once, in quarter 0
        float gself = __expf(lrelu(asrc[n * 2 + hh] + adn + ce * params[1]));
        float4 psf = h4[n * 8 + b4], usf = h4[n * 8 + b4 + 1];
        FMA4(A0, gself, psf) FMA4(A1, gself, usf)
        ssum += gself;
    }
    // merge the four edge-quarters: partner lanes tid^4 then tid^8 (same wave)
    A0.x += __shfl_xor(A0.x, 4, 64); A0.y += __shfl_xor(A0.y, 4, 64);
    A0.z += __shfl_xor(A0.z, 4, 64); A0.w += __shfl_xor(A0.w, 4, 64);
    A1.x += __shfl_xor(A1.x, 4, 64); A1.y += __shfl_xor(A1.y, 4, 64);
    A1.z += __shfl_xor(A1.z, 4, 64); A1.w += __shfl_xor(A1.w, 4, 64);
    ssum += __shfl_xor(ssum, 4, 64);
    A0.x += __shfl_xor(A0.x, 8, 64); A0.y += __shfl_xor(A0.y, 8, 64);
    A0.z += __shfl_xor(A0.z, 8, 64); A0.w += __shfl_xor(A0.w, 8, 64);
    A1.x += __shfl_xor(A1.x, 8, 64); A1.y += __shfl_xor(A1.y, 8, 64);
    A1.z += __shfl_xor(A1.z, 8, 64); A1.w += __shfl_xor(A1.w, 8, 64);
    ssum += __shfl_xor(ssum, 8, 64);
    if (quarter != 0) return;
    float inv = 1.f / (ssum + 1e-16f);
    float4 bv0 = ((const float4*)bias)[b4], bv1 = ((const float4*)bias)[b4 + 1];
    float4 v0 = make_float4(A0.x * inv + bv0.x, A0.y * inv + bv0.y,
                            A0.z * inv + bv0.z, A0.w * inv + bv0.w);
    float4 v1 = make_float4(A1.x * inv + bv1.x, A1.y * inv + bv1.y,
                            A1.z * inv + bv1.z, A1.w * inv + bv1.w);
    if (do_relu) {
        v0.x = fmaxf(v0.x, 0.f); v0.y = fmaxf(v0.y, 0.f);
        v0.z = fmaxf(v0.z, 0.f); v0.w = fmaxf(v0.w, 0.f);
        v1.x = fmaxf(v1.x, 0.f); v1.y = fmaxf(v1.y, 0.f);
        v1.w = fmaxf(v1.w, 0.f); v1.z = fmaxf(v1.z, 0.f);
    }
    if (!fuse) {
        ((float4*)out)[n * 8 + b4] = v0;
        ((float4*)out)[n * 8 + b4 + 1] = v1;
        return;
    }
    // ---- fused layer-2 linear: h2 = v @ W2 (chan lanes hold full 32-row) ----
    int lane = t & 63;
    int bse = lane & 48;                  // this node-group's lane base
    float h2[8] = {0.f, 0.f, 0.f, 0.f, 0.f, 0.f, 0.f, 0.f};
#pragma unroll
    for (int cc = 0; cc < 4; ++cc) {
        int sl = bse | cc;
        float vv[8];
        vv[0] = __shfl(v0.x, sl, 64); vv[1] = __shfl(v0.y, sl, 64);
        vv[2] = __shfl(v0.z, sl, 64); vv[3] = __shfl(v0.w, sl, 64);
        vv[4] = __shfl(v1.x, sl, 64); vv[5] = __shfl(v1.y, sl, 64);
        vv[6] = __shfl(v1.z, sl, 64); vv[7] = __shfl(v1.w, sl, 64);
#pragma unroll
        for (int m = 0; m < 8; ++m) {      // k = cc*8 + m, ascending (== k_linear order)
            const float* wrow = &w2s[(cc * 8 + m) * HC + chan * 8];
            float4 wa = *(const float4*)&wrow[0];
            float4 wb = *(const float4*)&wrow[4];
            h2[0] = fmaf(vv[m], wa.x, h2[0]); h2[1] = fmaf(vv[m], wa.y, h2[1]);
            h2[2] = fmaf(vv[m], wa.z, h2[2]); h2[3] = fmaf(vv[m], wa.w, h2[3]);
            h2[4] = fmaf(vv[m], wb.x, h2[4]); h2[5] = fmaf(vv[m], wb.y, h2[5]);
            h2[6] = fmaf(vv[m], wb.z, h2[6]); h2[7] = fmaf(vv[m], wb.w, h2[7]);
        }
    }
    ((float4*)out)[n * 8 + b4] = make_float4(h2[0], h2[1], h2[2], h2[3]);
    ((float4*)out)[n * 8 + b4 + 1] = make_float4(h2[4], h2[5], h2[6], h2[7]);
    float s2 = 0.f, d2 = 0.f;
#pragma unroll
    for (int j = 0; j < 8; ++j) {
        s2 = fmaf(h2[j], as2[chan * 8 + j], s2);
        d2 = fmaf(h2[j], ad2[chan * 8 + j], d2);
    }
    s2 += __shfl_xor(s2, 1, 64);           // chan0+1 = head0, chan2+3 = head1
    d2 += __shfl_xor(d2, 1, 64);
    if ((chan & 1) == 0) {
        asrc2[n * 2 + (chan >> 1)] = s2;
        adst2[n * 2 + (chan >> 1)] = d2;
    }
}

// ---------- pooling stage 1: streaming per-graph partial sums ----------

__global__ __launch_bounds__(1024)
void k_pool1(const float* __restrict__ feat, const int* __restrict__ batch,
             float* __restrict__ gsums) {
    __shared__ float gsum[GSPAN][32];
    int t = threadIdx.x;
    int c = t & 31, r = t >> 5;     // r in 0..31, 16 nodes each
    int base = blockIdx.x * NPB;
    if (t < GSPAN * 32) ((float*)gsum)[t] = 0.f;
    __syncthreads();
    int g0 = batch[base];
    float acc = 0.f;
    int gprev = -1;
    for (int i = 0; i < NPB / 32; ++i) {
        int n = base + r * (NPB / 32) + i;
        if (n >= N_NODES) break;
        int g = batch[n] - g0;
        if (g != gprev) {
            if (gprev >= 0) {
                if (gprev < GSPAN) atomicAdd(&gsum[gprev][c], acc);
                else unsafeAtomicAdd(&gsums[(g0 + gprev) * 32 + c], acc);
            }
            acc = 0.f;
            gprev = g;
        }
        acc += feat[(size_t)n * HC + c];
    }
    if (gprev >= 0) {
        if (gprev < GSPAN) atomicAdd(&gsum[gprev][c], acc);
        else unsafeAtomicAdd(&gsums[(g0 + gprev) * 32 + c], acc);
    }
    __syncthreads();
    if (t < GSPAN * 32) {
        int gi = t >> 5, cc = t & 31;
        float v = gsum[gi][cc];
        if (v != 0.f && g0 + gi < NGRAPH)
            unsafeAtomicAdd(&gsums[(g0 + gi) * 32 + cc], v);
    }
}

// ---------- pooling stage 2: mean + MLP head (tiny) ----------

__global__ void k_mlp(const float* __restrict__ gsums, const int* __restrict__ batch,
                      const float* __restrict__ Wf1, const float* __restrict__ bf1,
                      const float* __restrict__ Wf2, const float* __restrict__ bf2,
                      float* __restrict__ out) {
    int g = blockIdx.x;
    __shared__ int sse[2];
    __shared__ float emb[32];
    __shared__ float hid[32];
    if (threadIdx.x < 2) {
        int target = g + (int)threadIdx.x;
        int lo = 0, hi = N_NODES;
        while (lo < hi) {
            int mid = (lo + hi) >> 1;
            if (batch[mid] < target) lo = mid + 1; else hi = mid;
        }
        sse[threadIdx.x] = lo;
    }
    __syncthreads();
    int cnt = sse[1] - sse[0];
    if (threadIdx.x < 32)
        emb[threadIdx.x] = gsums[g * 32 + threadIdx.x] / (float)(cnt > 0 ? cnt : 1);
    __syncthreads();
    if (threadIdx.x < 32) {
        int j = threadIdx.x;
        float a = bf1[j];
        for (int k = 0; k < 32; ++k) a = fmaf(emb[k], Wf1[k * 32 + j], a);
        hid[j] = fmaxf(a, 0.f);
    }
    __syncthreads();
    if (threadIdx.x < 2) {
        int j = threadIdx.x;
        float o = bf2[j];
        for (int k = 0; k < 32; ++k) o = fmaf(hid[k], Wf2[k * 2 + j], o);
        out[g * 2 + j] = o;
    }
}

extern "C" void kernel_launch(void* const* d_in, const int* in_sizes, int n_in,
                              void* d_out, int out_size, void* d_ws, size_t ws_size,
                              hipStream_t stream) {
    const float* x   = (const float*)d_in[0];
    const int*   ei  = (const int*)d_in[1];
    const float* ea  = (const float*)d_in[2];
    const int* batch = (const int*)d_in[3];
    const float* W1  = (const float*)d_in[4];
    const float* as1 = (const float*)d_in[5];
    const float* ad1 = (const float*)d_in[6];
    const float* We1 = (const float*)d_in[7];
    const float* ae1 = (const float*)d_in[8];
    const float* b1  = (const float*)d_in[9];
    const float* W2  = (const float*)d_in[10];
    const float* as2 = (const float*)d_in[11];
    const float* ad2 = (const float*)d_in[12];
    const float* We2 = (const float*)d_in[13];
    const float* ae2 = (const float*)d_in[14];
    const float* b2  = (const float*)d_in[15];
    const float* Wf1 = (const float*)d_in[16];
    const float* bf1 = (const float*)d_in[17];
    const float* Wf2 = (const float*)d_in[18];
    const float* bf2 = (const float*)d_in[19];
    float* out = (float*)d_out;
    (void)in_sizes; (void)n_in; (void)out_size; (void)ws_size;

    const int* srcp = ei;
    const int* dstp = ei + N_EDGES;

    char* wsb = (char*)d_ws;
    size_t off = 0;
    auto alloc = [&](size_t bytes) -> char* {
        char* p = wsb + off;
        off = (off + bytes + 255) & ~(size_t)255;
        return p;
    };
    float* params = (float*)alloc(64);
    // region A: staged (NB2*CAP*8 = 28.8 MB), reused after k_scatter as hbuf + obuf
    char* regA = alloc((size_t)NB2 * CAP * 8 + 4096);
    int2*  staged = (int2*)regA;
    float* hbuf   = (float*)regA;
    float* obuf   = (float*)(regA + (size_t)N_NODES * HC * 4);
    int2*  epack  = (int2*)alloc((size_t)N_EDGES * 8);
    float* asrc   = (float*)alloc((size_t)N_NODES * 2 * 4);
    float* adst   = (float*)alloc((size_t)N_NODES * 2 * 4);
    float* asrc2  = (float*)alloc((size_t)N_NODES * 2 * 4);
    float* adst2  = (float*)alloc((size_t)N_NODES * 2 * 4);
    int*   gstart = (int*)alloc((size_t)(NB2 + 1) * 4);
    int*   gcur   = (int*)alloc((size_t)NB2 * GPAD * 4);
    int*   rowptr = (int*)alloc((size_t)(N_NODES + 1) * 4);
    float* gsums  = (float*)alloc((size_t)NGRAPH * HC * 4);

    const int nBlkB = (N_EDGES + EPB2 - 1) / EPB2;              // 391
    const int nBlkL = (N_NODES + 63) / 64;                      // 1563
    const int nBlkG = (N_NODES * 16 + 255) / 256;               // 6250
    const int nBlkP = (N_NODES + NPB - 1) / NPB;                // 196

    // fixed-capacity bucket sort (no pre-histogram pass)
    k_init<<<1, 1024, 0, stream>>>(gcur, params, gsums);
    k_bucket<<<nBlkB, BTHR, 0, stream>>>(srcp, dstp, ea, gcur, staged, params);
    k_setup<<<1, 256, 0, stream>>>(We1, ae1, We2, ae2, params, gcur, gstart, rowptr);
    k_scatter<<<NB2, 1024, 0, stream>>>(staged, gcur, gstart, rowptr, epack);

    // ----- layer 1 (+ fused layer-2 linear in epilogue) -----
    k_linear<F_IN><<<nBlkL, 256, 0, stream>>>(x, W1, as1, ad1, hbuf, asrc, adst);
    k_gat<<<nBlkG, 256, 0, stream>>>(rowptr, epack, hbuf, asrc, adst, params, 2, b1, 1,
                                     obuf, 1, W2, as2, ad2, asrc2, adst2);

    // ----- layer 2 (reads h2 in obuf; writes final features into hbuf) -----
    k_gat<<<nBlkG, 256, 0, stream>>>(rowptr, epack, obuf, asrc2, adst2, params, 4, b2, 0,
                                     hbuf, 0, W2, as2, ad2, asrc2, adst2);

    // ----- pool (streaming partials) + MLP head -----
    k_pool1<<<nBlkP, 1024, 0, stream>>>(hbuf, batch, gsums);
    k_mlp<<<NGRAPH, 64, 0, stream>>>(gsums, batch, Wf1, bf1, Wf2, bf2, out);
}

// Round 9
// 338.286 us; speedup vs baseline: 1.2528x; 1.0385x over previous
//
#include <hip/hip_runtime.h>
#include <hip/hip_fp16.h>

#define N_NODES 100000
#define N_EDGES 3200000
#define F_IN    128
#define HC      32      // H*C
#define CH      16      // C per head
#define NGRAPH  64
#define NEG     0.2f

#define BSH   8                                   // 256 nodes per bucket
#define BNODE (1 << BSH)
#define NB2   ((N_NODES + BNODE - 1) >> BSH)      // 391 buckets
#define CAP   9216                                // fixed staged slot per bucket
#define EPB2  8192                                // edges per k_bucket block
#define BTHR  1024                                // k_bucket threads
#define HEPB  4096                                // edges per LDS-reorder half-pass
#define GPAD  16                                  // gcur stride (1 line/bucket)
#define CHK   4096                                // k_scatter chunk (LDS reorder)
#define NPB   512                                 // nodes per k_pool1 block
#define GSPAN 16                                  // max graphs spanned per pool block (LDS bins)

__device__ __forceinline__ float lrelu(float x) { return x > 0.f ? x : NEG * x; }

// ---------- init: fixed bucket bases + params + gsums zero ----------

__global__ void k_init(int* __restrict__ gcur, float* __restrict__ params,
                       float* __restrict__ gsums) {
    int t = threadIdx.x;
    if (t < NB2) gcur[t * GPAD] = t * CAP;
    if (t < 16) params[t] = 0.f;
    gsums[t] = 0.f;                 // 1024 threads
    gsums[t + 1024] = 0.f;          // total 2048 = NGRAPH*HC
}

// ---------- pass A: bucket scatter with LDS reorder for coalesced staged stores ----------

__global__ __launch_bounds__(1024)
void k_bucket(const int* __restrict__ src, const int* __restrict__ dst,
              const float* __restrict__ ea, int* __restrict__ gcur,
              int2* __restrict__ staged, float* __restrict__ params) {
    __shared__ int lcur[NB2];
    __shared__ int lscan[512];
    __shared__ int gbase[NB2];
    __shared__ short rbkt[HEPB];
    __shared__ int2 recs[HEPB];
    int t = threadIdx.x;
    float acc = 0.f;
    for (int half = 0; half < 2; ++half) {
        int base = blockIdx.x * EPB2 + half * HEPB;
        for (int i = t; i < NB2; i += BTHR) lcur[i] = 0;
        __syncthreads();
        int  myb[HEPB / BTHR];
        int  myrank[HEPB / BTHR];
        int2 myrec[HEPB / BTHR];
#pragma unroll
        for (int i = 0; i < HEPB / BTHR; ++i) {
            int e = base + i * BTHR + t;
            myb[i] = -1;
            if (e < N_EDGES) {
                int dv = dst[e];
                float eav = ea[e];
                acc += eav;
                myb[i] = dv >> BSH;
                myrank[i] = atomicAdd(&lcur[myb[i]], 1);
                myrec[i] = make_int2((src[e] << BSH) | (dv & (BNODE - 1)),
                                     __float_as_int(eav));
            }
        }
        __syncthreads();
        if (t < 512) lscan[t] = (t < NB2) ? lcur[t] : 0;
        __syncthreads();
        for (int off = 1; off < 512; off <<= 1) {
            int u = 0;
            if (t < 512 && t >= off) u = lscan[t - off];
            __syncthreads();
            if (t < 512) lscan[t] += u;
            __syncthreads();
        }
        if (t < NB2 && lcur[t] > 0) gbase[t] = atomicAdd(&gcur[t * GPAD], lcur[t]);
        __syncthreads();
#pragma unroll
        for (int i = 0; i < HEPB / BTHR; ++i) {
            if (myb[i] >= 0) {
                int p = lscan[myb[i]] - lcur[myb[i]] + myrank[i];
                recs[p] = myrec[i];
                rbkt[p] = (short)myb[i];
            }
        }
        __syncthreads();
        int tot = lscan[511];
        for (int p = t; p < tot; p += BTHR) {
            int b = rbkt[p];
            int ex = lscan[b] - lcur[b];
            staged[gbase[b] + (p - ex)] = recs[p];
        }
        __syncthreads();
    }
    for (int m = 32; m >= 1; m >>= 1) acc += __shfl_xor(acc, m, 64);
    __shared__ float sh[BTHR / 64];
    int lane = t & 63, wid = t >> 6;
    if (lane == 0) sh[wid] = acc;
    __syncthreads();
    if (t == 0) {
        float s = 0.f;
        for (int i = 0; i < BTHR / 64; ++i) s += sh[i];
        unsafeAtomicAdd(&params[0], s);
    }
}

// ---------- params precompute + bucket prefix scan ----------

__global__ void k_setup(const float* __restrict__ We1, const float* __restrict__ ae1,
                        const float* __restrict__ We2, const float* __restrict__ ae2,
                        float* __restrict__ params, const int* __restrict__ gcur,
                        int* __restrict__ gstart, int* __restrict__ rowptr) {
    int t = threadIdx.x;
    if (t < 2) {
        float c1 = 0.f, c2 = 0.f;
        for (int c = 0; c < CH; ++c) {
            c1 += We1[t * CH + c] * ae1[t * CH + c];
            c2 += We2[t * CH + c] * ae2[t * CH + c];
        }
        params[2 + t] = c1;
        params[4 + t] = c2;
        if (t == 0) params[1] = params[0] / (float)N_EDGES;
    }
    __shared__ int sh[256];
    int v[2];
    int s = 0;
    for (int j = 0; j < 2; ++j) {
        int i = t * 2 + j;
        v[j] = (i < NB2) ? (gcur[i * GPAD] - i * CAP) : 0;
        s += v[j];
    }
    sh[t] = s;
    __syncthreads();
    for (int off = 1; off < 256; off <<= 1) {
        int u = (t >= off) ? sh[t - off] : 0;
        __syncthreads();
        sh[t] += u;
        __syncthreads();
    }
    int ex = sh[t] - s;
    for (int j = 0; j < 2; ++j) {
        int i = t * 2 + j;
        if (i < NB2) { gstart[i] = ex; ex += v[j]; }
    }
    if (t == 255) {
        gstart[NB2] = N_EDGES;
        rowptr[N_NODES] = N_EDGES;
    }
}

// ---------- pass B: hist+scan, then CHUNKED LDS-reorder emission of epack ----------

__global__ __launch_bounds__(1024)
void k_scatter(const int2* __restrict__ staged, const int* __restrict__ gcur,
               const int* __restrict__ gstart,
               int* __restrict__ rowptr, int2* __restrict__ epack) {
    __shared__ int cntl[BNODE];
    __shared__ int scanb[BNODE];
    __shared__ int cur[BNODE];
    __shared__ int cchist[BNODE];
    __shared__ int cexcl[BNODE];
    __shared__ short rbkt[CHK];
    __shared__ int2 recs[CHK];
    int b = blockIdx.x, t = threadIdx.x;
    int nbase = b << BSH;
    int bcount = N_NODES - nbase;
    if (bcount > BNODE) bcount = BNODE;
    int sbase = b * CAP;
    int en = gcur[b * GPAD];
    int st_true = gstart[b];
    if (t < BNODE) cntl[t] = 0;
    __syncthreads();
    for (int e = sbase + t; e < en; e += 1024)
        atomicAdd(&cntl[staged[e].x & (BNODE - 1)], 1);
    __syncthreads();
    if (t < BNODE) scanb[t] = cntl[t];
    __syncthreads();
    for (int off = 1; off < BNODE; off <<= 1) {
        int u = (t < BNODE && t >= off) ? scanb[t - off] : 0;
        __syncthreads();
        if (t < BNODE) scanb[t] += u;
        __syncthreads();
    }
    if (t < BNODE) {
        int ex = st_true + scanb[t] - cntl[t];   // exclusive, global
        cur[t] = ex;
        if (t < bcount) rowptr[nbase + t] = ex;
    }
    __syncthreads();
    int count = en - sbase;
    for (int cb = 0; cb < count; cb += CHK) {
        int clen = count - cb;
        if (clen > CHK) clen = CHK;
        if (t < BNODE) cchist[t] = 0;
        __syncthreads();
        int  mylo[CHK / 1024];
        int  myrank[CHK / 1024];
        int2 myrec[CHK / 1024];
#pragma unroll
        for (int i = 0; i < CHK / 1024; ++i) {
            int p = i * 1024 + t;
            mylo[i] = -1;
            if (p < clen) {
                int2 r = staged[sbase + cb + p];   // second read: L2-hot window
                mylo[i] = r.x & (BNODE - 1);
                myrank[i] = atomicAdd(&cchist[mylo[i]], 1);
                myrec[i] = r;
            }
        }
        __syncthreads();
        if (t < BNODE) cexcl[t] = cchist[t];
        __syncthreads();
        for (int off = 1; off < BNODE; off <<= 1) {
            int u = (t < BNODE && t >= off) ? cexcl[t - off] : 0;
            __syncthreads();
            if (t < BNODE) cexcl[t] += u;
            __syncthreads();
        }
        if (t < BNODE) cexcl[t] -= cchist[t];     // exclusive within chunk
        __syncthreads();
#pragma unroll
        for (int i = 0; i < CHK / 1024; ++i) {
            if (mylo[i] >= 0) {
                int p = cexcl[mylo[i]] + myrank[i];
                recs[p] = myrec[i];
                rbkt[p] = (short)mylo[i];
            }
        }
        __syncthreads();
        for (int p = t; p < clen; p += 1024) {
            int lo = rbkt[p];
            epack[cur[lo] + (p - cexcl[lo])] = recs[p];
        }
        __syncthreads();
        if (t < BNODE) cur[t] += cchist[t];
        __syncthreads();
    }
}

// ---------- dense: h = x @ W (LDS-tiled), fp16 h-table out + fp32 asrc/adst ----------

#define COLS(ac, xv)                                                     \
    ac[0] = fmaf(xv.x, w0.x, ac[0]); ac[1] = fmaf(xv.x, w0.y, ac[1]);    \
    ac[2] = fmaf(xv.x, w0.z, ac[2]); ac[3] = fmaf(xv.x, w0.w, ac[3]);    \
    ac[0] = fmaf(xv.y, w1.x, ac[0]); ac[1] = fmaf(xv.y, w1.y, ac[1]);    \
    ac[2] = fmaf(xv.y, w1.z, ac[2]); ac[3] = fmaf(xv.y, w1.w, ac[3]);    \
    ac[0] = fmaf(xv.z, w2.x, ac[0]); ac[1] = fmaf(xv.z, w2.y, ac[1]);    \
    ac[2] = fmaf(xv.z, w2.z, ac[2]); ac[3] = fmaf(xv.z, w2.w, ac[3]);    \
    ac[0] = fmaf(xv.w, w3.x, ac[0]); ac[1] = fmaf(xv.w, w3.y, ac[1]);    \
    ac[2] = fmaf(xv.w, w3.z, ac[2]); ac[3] = fmaf(xv.w, w3.w, ac[3]);

template <int FIN>
__global__ __launch_bounds__(256)
void k_linear(const float* __restrict__ x, const float* __restrict__ W,
              const float* __restrict__ a_src, const float* __restrict__ a_dst,
              __half* __restrict__ h16, float* __restrict__ asrc,
              float* __restrict__ adst) {
    constexpr int PAD = FIN + 4;
    __shared__ float ws[FIN * HC];
    __shared__ float xs[64 * PAD];
    int t = threadIdx.x;
    int nbase = blockIdx.x * 64;
    int bcount = N_NODES - nbase;
    if (bcount > 64) bcount = 64;

    for (int i = t; i < FIN * HC / 4; i += 256)
        ((float4*)ws)[i] = ((const float4*)W)[i];
    const float4* xg = (const float4*)(x + (size_t)nbase * FIN);
    int nf4 = bcount * FIN / 4;
    for (int i = t; i < 64 * FIN / 4; i += 256) {
        if (i < nf4) {
            float4 v = xg[i];
            int flat = i * 4;
            int row = flat / FIN, col = flat % FIN;
            *(float4*)&xs[row * PAD + col] = v;
        }
    }
    __syncthreads();

    int cg = t & 7, np = t >> 3;
    int n0 = np * 2, n1 = n0 + 1;
    float acc0[4] = {0.f, 0.f, 0.f, 0.f};
    float acc1[4] = {0.f, 0.f, 0.f, 0.f};
#pragma unroll
    for (int k = 0; k < FIN; k += 4) {
        float4 xa = *(const float4*)&xs[n0 * PAD + k];
        float4 xb = *(const float4*)&xs[n1 * PAD + k];
        const float4* wp = (const float4*)&ws[k * HC] + cg;
        float4 w0 = wp[0], w1 = wp[8], w2 = wp[16], w3 = wp[24];
        COLS(acc0, xa)
        COLS(acc1, xb)
    }

    int hh = cg >> 2;
    float s0 = 0.f, d0 = 0.f, s1 = 0.f, d1 = 0.f;
#pragma unroll
    for (int j = 0; j < 4; ++j) {
        float av = a_src[hh * CH + (cg & 3) * 4 + j];
        float dv = a_dst[hh * CH + (cg & 3) * 4 + j];
        s0 = fmaf(acc0[j], av, s0); d0 = fmaf(acc0[j], dv, d0);
        s1 = fmaf(acc1[j], av, s1); d1 = fmaf(acc1[j], dv, d1);
    }
    s0 += __shfl_xor(s0, 1, 64); s0 += __shfl_xor(s0, 2, 64);
    d0 += __shfl_xor(d0, 1, 64); d0 += __shfl_xor(d0, 2, 64);
    s1 += __shfl_xor(s1, 1, 64); s1 += __shfl_xor(s1, 2, 64);
    d1 += __shfl_xor(d1, 1, 64); d1 += __shfl_xor(d1, 2, 64);

    if (n0 < bcount) {
        __half2 pa = __floats2half2_rn(acc0[0], acc0[1]);
        __half2 pb = __floats2half2_rn(acc0[2], acc0[3]);
        *(uint2*)&h16[(size_t)(nbase + n0) * HC + cg * 4] =
            make_uint2(*(unsigned*)&pa, *(unsigned*)&pb);
        if ((cg & 3) == 0) {
            asrc[(nbase + n0) * 2 + hh] = s0;
            adst[(nbase + n0) * 2 + hh] = d0;
        }
    }
    if (n1 < bcount) {
        __half2 pa = __floats2half2_rn(acc1[0], acc1[1]);
        __half2 pb = __floats2half2_rn(acc1[2], acc1[3]);
        *(uint2*)&h16[(size_t)(nbase + n1) * HC + cg * 4] =
            make_uint2(*(unsigned*)&pa, *(unsigned*)&pb);
        if ((cg & 3) == 0) {
            asrc[(nbase + n1) * 2 + hh] = s1;
            adst[(nbase + n1) * 2 + hh] = d1;
        }
    }
}

// ---------- fused GAT layer: 16 lanes/node, fp16 h gathers ----------
// FUSE=1 (layer 1): epilogue computes h2 = relu(out) @ W2 in fp32 via in-wave
// shfl, writes h2 as fp16 table + fp32 asrc2/adst2 (logits stay fp32-exact).
// FUSE=0 (layer 2): writes final fp32 features for pooling.

#define FMA4(ACC, WGT, VEC)                                                      \
    ACC.x = fmaf(WGT, VEC.x, ACC.x); ACC.y = fmaf(WGT, VEC.y, ACC.y);            \
    ACC.z = fmaf(WGT, VEC.z, ACC.z); ACC.w = fmaf(WGT, VEC.w, ACC.w);

__device__ __forceinline__ void unpack8(uint4 hv, float4& p, float4& u) {
    float2 f0 = __half22float2(*(__half2*)&hv.x);
    float2 f1 = __half22float2(*(__half2*)&hv.y);
    float2 f2 = __half22float2(*(__half2*)&hv.z);
    float2 f3 = __half22float2(*(__half2*)&hv.w);
    p = make_float4(f0.x, f0.y, f1.x, f1.y);
    u = make_float4(f2.x, f2.y, f3.x, f3.y);
}

template <int FUSE>
__global__ __launch_bounds__(256)
void k_gat(const int* __restrict__ rowptr, const int2* __restrict__ epack,
           const __half* __restrict__ h16,
           const float* __restrict__ asrc, const float* __restrict__ adst,
           const float* __restrict__ params, int ceoff,
           const float* __restrict__ bias, int do_relu,
           float* __restrict__ outf, __half* __restrict__ outh,
           const float* __restrict__ W2,
           const float* __restrict__ as2, const float* __restrict__ ad2,
           float* __restrict__ asrc2, float* __restrict__ adst2) {
    __shared__ float w2s[FUSE ? HC * HC : 4];
    int t = threadIdx.x;
    if (FUSE) {
        for (int i = t; i < HC * HC / 4; i += 256)
            ((float4*)w2s)[i] = ((const float4*)W2)[i];
        __syncthreads();
    }
    int tid = blockIdx.x * blockDim.x + t;
    int n = tid >> 4;
    if (n >= N_NODES) return;
    int q = tid & 15;
    int chan = q & 3, quarter = q >> 2, hh = chan >> 1;
    int st = rowptr[n], en = rowptr[n + 1];
    int len = en - st;
    int q0 = st + ((len * quarter) >> 2);
    int q1 = st + ((len * (quarter + 1)) >> 2);
    float ce = params[ceoff + hh];
    float adn = adst[n * 2 + hh];
    const uint4* h4v = (const uint4*)h16;     // one uint4 = 8 halfs = this lane's channels
    float4 A0 = make_float4(0.f, 0.f, 0.f, 0.f);
    float4 A1 = make_float4(0.f, 0.f, 0.f, 0.f);
    float ssum = 0.f;
    for (int e = q0; e < q1; e += 4) {
        int e1 = e + 1, e2 = e + 2, e3 = e + 3;
        int i1 = e1 < q1 ? e1 : q1 - 1;
        int i2 = e2 < q1 ? e2 : q1 - 1;
        int i3 = e3 < q1 ? e3 : q1 - 1;
        int2 r0 = epack[e], r1 = epack[i1], r2 = epack[i2], r3 = epack[i3];
        int s0 = r0.x >> BSH, s1 = r1.x >> BSH, s2 = r2.x >> BSH, s3 = r3.x >> BSH;
        float a0 = asrc[s0 * 2 + hh], a1 = asrc[s1 * 2 + hh];
        float a2 = asrc[s2 * 2 + hh], a3 = asrc[s3 * 2 + hh];
        uint4 hv0 = h4v[s0 * 4 + chan];
        uint4 hv1 = h4v[s1 * 4 + chan];
        uint4 hv2 = h4v[s2 * 4 + chan];
        uint4 hv3 = h4v[s3 * 4 + chan];
        float g0 = __expf(lrelu(a0 + adn + ce * __int_as_float(r0.y)));
        float g1 = __expf(lrelu(a1 + adn + ce * __int_as_float(r1.y)));
        float g2 = __expf(lrelu(a2 + adn + ce * __int_as_float(r2.y)));
        float g3 = __expf(lrelu(a3 + adn + ce * __int_as_float(r3.y)));
        g1 = (e1 < q1) ? g1 : 0.f;
        g2 = (e2 < q1) ? g2 : 0.f;
        g3 = (e3 < q1) ? g3 : 0.f;
        float4 p0, u0, p1, u1, p2, u2, p3, u3;
        unpack8(hv0, p0, u0); unpack8(hv1, p1, u1);
        unpack8(hv2, p2, u2); unpack8(hv3, p3, u3);
        FMA4(A0, g0, p0) FMA4(A1, g0, u0) ssum += g0;
        FMA4(A0, g1, p1) FMA4(A1, g1, u1) ssum += g1;
        FMA4(A0, g2, p2) FMA4(A1, g2, u2) ssum += g2;
        FMA4(A0, g3, p3) FMA4(A1, g3, u3) ssum += g3;
    }
    if (quarter == 0) {
        // self-loop (eattr = mean) counted once, in quarter 0
        float gself = __expf(lrelu(asrc[n * 2 + hh] + adn + ce * params[1]));
        float4 psf, usf;
        unpack8(h4v[n * 4 + chan], psf, usf);
        FMA4(A0, gself, psf) FMA4(A1, gself, usf)
        ssum += gself;
    }
    // merge the four edge-quarters: partner lanes tid^4 then tid^8 (same wave)
    A0.x += __shfl_xor(A0.x, 4, 64); A0.y += __shfl_xor(A0.y, 4, 64);
    A0.z += __shfl_xor(A0.z, 4, 64); A0.w += __shfl_xor(A0.w, 4, 64);
    A1.x += __shfl_xor(A1.x, 4, 64); A1.y += __shfl_xor(A1.y, 4, 64);
    A1.z += __shfl_xor(A1.z, 4, 64); A1.w += __shfl_xor(A1.w, 4, 64);
    ssum += __shfl_xor(ssum, 4, 64);
    A0.x += __shfl_xor(A0.x, 8, 64); A0.y += __shfl_xor(A0.y, 8, 64);
    A0.z += __shfl_xor(A0.z, 8, 64); A0.w += __shfl_xor(A0.w, 8, 64);
    A1.x += __shfl_xor(A1.x, 8, 64); A1.y += __shfl_xor(A1.y, 8, 64);
    A1.z += __shfl_xor(A1.z, 8, 64); A1.w += __shfl_xor(A1.w, 8, 64);
    ssum += __shfl_xor(ssum, 8, 64);
    if (quarter != 0) return;
    float inv = 1.f / (ssum + 1e-16f);
    int b4 = chan * 2;
    float4 bv0 = ((const float4*)bias)[b4], bv1 = ((const float4*)bias)[b4 + 1];
    float4 v0 = make_float4(A0.x * inv + bv0.x, A0.y * inv + bv0.y,
                            A0.z * inv + bv0.z, A0.w * inv + bv0.w);
    float4 v1 = make_float4(A1.x * inv + bv1.x, A1.y * inv + bv1.y,
                            A1.z * inv + bv1.z, A1.w * inv + bv1.w);
    if (do_relu) {
        v0.x = fmaxf(v0.x, 0.f); v0.y = fmaxf(v0.y, 0.f);
        v0.z = fmaxf(v0.z, 0.f); v0.w = fmaxf(v0.w, 0.f);
        v1.x = fmaxf(v1.x, 0.f); v1.y = fmaxf(v1.y, 0.f);
        v1.z = fmaxf(v1.z, 0.f); v1.w = fmaxf(v1.w, 0.f);
    }
    if (!FUSE) {
        ((float4*)outf)[n * 8 + b4] = v0;
        ((float4*)outf)[n * 8 + b4 + 1] = v1;
        return;
    }
    // ---- fused layer-2 linear (fp32): h2 = v @ W2; chan lanes hold full row ----
    int lane = t & 63;
    int bse = lane & 48;                  // node-group lane base (quarter-0 chan lanes)
    float h2[8] = {0.f, 0.f, 0.f, 0.f, 0.f, 0.f, 0.f, 0.f};
#pragma unroll
    for (int cc = 0; cc < 4; ++cc) {
        int sl = bse | cc;
        float vv[8];
        vv[0] = __shfl(v0.x, sl, 64); vv[1] = __shfl(v0.y, sl, 64);
        vv[2] = __shfl(v0.z, sl, 64); vv[3] = __shfl(v0.w, sl, 64);
        vv[4] = __shfl(v1.x, sl, 64); vv[5] = __shfl(v1.y, sl, 64);
        vv[6] = __shfl(v1.z, sl, 64); vv[7] = __shfl(v1.w, sl, 64);
#pragma unroll
        for (int m = 0; m < 8; ++m) {      // k ascending (== k_linear order)
            const float* wrow = &w2s[(cc * 8 + m) * HC + chan * 8];
            float4 wa = *(const float4*)&wrow[0];
            float4 wb = *(const float4*)&wrow[4];
            h2[0] = fmaf(vv[m], wa.x, h2[0]); h2[1] = fmaf(vv[m], wa.y, h2[1]);
            h2[2] = fmaf(vv[m], wa.z, h2[2]); h2[3] = fmaf(vv[m], wa.w, h2[3]);
            h2[4] = fmaf(vv[m], wb.x, h2[4]); h2[5] = fmaf(vv[m], wb.y, h2[5]);
            h2[6] = fmaf(vv[m], wb.z, h2[6]); h2[7] = fmaf(vv[m], wb.w, h2[7]);
        }
    }
    __half2 q0h = __floats2half2_rn(h2[0], h2[1]);
    __half2 q1h = __floats2half2_rn(h2[2], h2[3]);
    __half2 q2h = __floats2half2_rn(h2[4], h2[5]);
    __half2 q3h = __floats2half2_rn(h2[6], h2[7]);
    *(uint4*)&outh[(size_t)n * HC + chan * 8] =
        make_uint4(*(unsigned*)&q0h, *(unsigned*)&q1h,
                   *(unsigned*)&q2h, *(unsigned*)&q3h);
    float s2 = 0.f, d2 = 0.f;
#pragma unroll
    for (int j = 0; j < 8; ++j) {
        s2 = fmaf(h2[j], as2[chan * 8 + j], s2);
        d2 = fmaf(h2[j], ad2[chan * 8 + j], d2);
    }
    s2 += __shfl_xor(s2, 1, 64);           // chan0+1 = head0, chan2+3 = head1
    d2 += __shfl_xor(d2, 1, 64);
    if ((chan & 1) == 0) {
        asrc2[n * 2 + (chan >> 1)] = s2;
        adst2[n * 2 + (chan >> 1)] = d2;
    }
}

// ---------- pooling stage 1: streaming per-graph partial sums ----------

__global__ __launch_bounds__(1024)
void k_pool1(const float* __restrict__ feat, const int* __restrict__ batch,
             float* __restrict__ gsums) {
    __shared__ float gsum[GSPAN][32];
    int t = threadIdx.x;
    int c = t & 31, r = t >> 5;     // r in 0..31, 16 nodes each
    int base = blockIdx.x * NPB;
    if (t < GSPAN * 32) ((float*)gsum)[t] = 0.f;
    __syncthreads();
    int g0 = batch[base];
    float acc = 0.f;
    int gprev = -1;
    for (int i = 0; i < NPB / 32; ++i) {
        int n = base + r * (NPB / 32) + i;
        if (n >= N_NODES) break;
        int g = batch[n] - g0;
        if (g != gprev) {
            if (gprev >= 0) {
                if (gprev < GSPAN) atomicAdd(&gsum[gprev][c], acc);
                else unsafeAtomicAdd(&gsums[(g0 + gprev) * 32 + c], acc);
            }
            acc = 0.f;
            gprev = g;
        }
        acc += feat[(size_t)n * HC + c];
    }
    if (gprev >= 0) {
        if (gprev < GSPAN) atomicAdd(&gsum[gprev][c], acc);
        else unsafeAtomicAdd(&gsums[(g0 + gprev) * 32 + c], acc);
    }
    __syncthreads();
    if (t < GSPAN * 32) {
        int gi = t >> 5, cc = t & 31;
        float v = gsum[gi][cc];
        if (v != 0.f && g0 + gi < NGRAPH)
            unsafeAtomicAdd(&gsums[(g0 + gi) * 32 + cc], v);
    }
}

// ---------- pooling stage 2: mean + MLP head (tiny) ----------

__global__ void k_mlp(const float* __restrict__ gsums, const int* __restrict__ batch,
                      const float* __restrict__ Wf1, const float* __restrict__ bf1,
                      const float* __restrict__ Wf2, const float* __restrict__ bf2,
                      float* __restrict__ out) {
    int g = blockIdx.x;
    __shared__ int sse[2];
    __shared__ float emb[32];
    __shared__ float hid[32];
    if (threadIdx.x < 2) {
        int target = g + (int)threadIdx.x;
        int lo = 0, hi = N_NODES;
        while (lo < hi) {
            int mid = (lo + hi) >> 1;
            if (batch[mid] < target) lo = mid + 1; else hi = mid;
        }
        sse[threadIdx.x] = lo;
    }
    __syncthreads();
    int cnt = sse[1] - sse[0];
    if (threadIdx.x < 32)
        emb[threadIdx.x] = gsums[g * 32 + threadIdx.x] / (float)(cnt > 0 ? cnt : 1);
    __syncthreads();
    if (threadIdx.x < 32) {
        int j = threadIdx.x;
        float a = bf1[j];
        for (int k = 0; k < 32; ++k) a = fmaf(emb[k], Wf1[k * 32 + j], a);
        hid[j] = fmaxf(a, 0.f);
    }
    __syncthreads();
    if (threadIdx.x < 2) {
        int j = threadIdx.x;
        float o = bf2[j];
        for (int k = 0; k < 32; ++k) o = fmaf(hid[k], Wf2[k * 2 + j], o);
        out[g * 2 + j] = o;
    }
}

extern "C" void kernel_launch(void* const* d_in, const int* in_sizes, int n_in,
                              void* d_out, int out_size, void* d_ws, size_t ws_size,
                              hipStream_t stream) {
    const float* x   = (const float*)d_in[0];
    const int*   ei  = (const int*)d_in[1];
    const float* ea  = (const float*)d_in[2];
    const int* batch = (const int*)d_in[3];
    const float* W1  = (const float*)d_in[4];
    const float* as1 = (const float*)d_in[5];
    const float* ad1 = (const float*)d_in[6];
    const float* We1 = (const float*)d_in[7];
    const float* ae1 = (const float*)d_in[8];
    const float* b1  = (const float*)d_in[9];
    const float* W2  = (const float*)d_in[10];
    const float* as2 = (const float*)d_in[11];
    const float* ad2 = (const float*)d_in[12];
    const float* We2 = (const float*)d_in[13];
    const float* ae2 = (const float*)d_in[14];
    const float* b2  = (const float*)d_in[15];
    const float* Wf1 = (const float*)d_in[16];
    const float* bf1 = (const float*)d_in[17];
    const float* Wf2 = (const float*)d_in[18];
    const float* bf2 = (const float*)d_in[19];
    float* out = (float*)d_out;
    (void)in_sizes; (void)n_in; (void)out_size; (void)ws_size;

    const int* srcp = ei;
    const int* dstp = ei + N_EDGES;

    char* wsb = (char*)d_ws;
    size_t off = 0;
    auto alloc = [&](size_t bytes) -> char* {
        char* p = wsb + off;
        off = (off + bytes + 255) & ~(size_t)255;
        return p;
    };
    float* params = (float*)alloc(64);
    // region A: staged (28.8 MB); reused after k_scatter as fp32 final-feature buf
    char* regA = alloc((size_t)NB2 * CAP * 8 + 4096);
    int2*  staged = (int2*)regA;
    float* feat   = (float*)regA;
    int2*  epack  = (int2*)alloc((size_t)N_EDGES * 8);
    __half* h16a  = (__half*)alloc((size_t)N_NODES * HC * 2);
    __half* h16b  = (__half*)alloc((size_t)N_NODES * HC * 2);
    float* asrc   = (float*)alloc((size_t)N_NODES * 2 * 4);
    float* adst   = (float*)alloc((size_t)N_NODES * 2 * 4);
    float* asrc2  = (float*)alloc((size_t)N_NODES * 2 * 4);
    float* adst2  = (float*)alloc((size_t)N_NODES * 2 * 4);
    int*   gstart = (int*)alloc((size_t)(NB2 + 1) * 4);
    int*   gcur   = (int*)alloc((size_t)NB2 * GPAD * 4);
    int*   rowptr = (int*)alloc((size_t)(N_NODES + 1) * 4);
    float* gsums  = (float*)alloc((size_t)NGRAPH * HC * 4);

    const int nBlkB = (N_EDGES + EPB2 - 1) / EPB2;              // 391
    const int nBlkL = (N_NODES + 63) / 64;                      // 1563
    const int nBlkG = (N_NODES * 16 + 255) / 256;               // 6250
    const int nBlkP = (N_NODES + NPB - 1) / NPB;                // 196

    // fixed-capacity bucket sort (no pre-histogram pass)
    k_init<<<1, 1024, 0, stream>>>(gcur, params, gsums);
    k_bucket<<<nBlkB, BTHR, 0, stream>>>(srcp, dstp, ea, gcur, staged, params);
    k_setup<<<1, 256, 0, stream>>>(We1, ae1, We2, ae2, params, gcur, gstart, rowptr);
    k_scatter<<<NB2, 1024, 0, stream>>>(staged, gcur, gstart, rowptr, epack);

    // ----- layer 1 (+ fused layer-2 linear in epilogue, fp16 tables) -----
    k_linear<F_IN><<<nBlkL, 256, 0, stream>>>(x, W1, as1, ad1, h16a, asrc, adst);
    k_gat<1><<<nBlkG, 256, 0, stream>>>(rowptr, epack, h16a, asrc, adst, params, 2, b1, 1,
                                        nullptr, h16b, W2, as2, ad2, asrc2, adst2);

    // ----- layer 2 (reads fp16 h2; writes fp32 features into staged region) -----
    k_gat<0><<<nBlkG, 256, 0, stream>>>(rowptr, epack, h16b, asrc2, adst2, params, 4, b2, 0,
                                        feat, nullptr, W2, as2, ad2, asrc2, adst2);

    // ----- pool (streaming partials) + MLP head -----
    k_pool1<<<nBlkP, 1024, 0, stream>>>(feat, batch, gsums);
    k_mlp<<<NGRAPH, 64, 0, stream>>>(gsums, batch, Wf1, bf1, Wf2, bf2, out);
}

// Round 10
// 334.038 us; speedup vs baseline: 1.2687x; 1.0127x over previous
//
#include <hip/hip_runtime.h>
#include <hip/hip_fp16.h>

#define N_NODES 100000
#define N_EDGES 3200000
#define F_IN    128
#define HC      32      // H*C
#define CH      16      // C per head
#define NGRAPH  64
#define NEG     0.2f

#define BSH   8                                   // 256 nodes per bucket
#define BNODE (1 << BSH)
#define NB2   ((N_NODES + BNODE - 1) >> BSH)      // 391 buckets
#define CAP   9216                                // fixed staged slot per bucket
#define EPB   4096                                // edges per k_bucket block (single pass)
#define BTHR  1024                                // k_bucket threads
#define GPAD  16                                  // gcur stride (1 line/bucket)
#define CHK   4096                                // k_scatter chunk (LDS reorder)
#define NPB   512                                 // nodes per k_pool1 block
#define GSPAN 16                                  // max graphs spanned per pool block (LDS bins)

__device__ __forceinline__ float lrelu(float x) { return x > 0.f ? x : NEG * x; }

// inclusive scan over the 64-lane wave
__device__ __forceinline__ int wscan(int v) {
#pragma unroll
    for (int off = 1; off < 64; off <<= 1) {
        int u = __shfl_up(v, off, 64);
        if ((int)(threadIdx.x & 63) >= off) v += u;
    }
    return v;
}

// ---------- init: fixed bucket bases + params + gsums zero ----------

__global__ void k_init(int* __restrict__ gcur, float* __restrict__ params,
                       float* __restrict__ gsums) {
    int t = threadIdx.x;
    if (t < NB2) gcur[t * GPAD] = t * CAP;
    if (t < 16) params[t] = 0.f;
    gsums[t] = 0.f;                 // 1024 threads
    gsums[t + 1024] = 0.f;          // total 2048 = NGRAPH*HC
}

// ---------- pass A: bucket scatter, single 4096-edge pass, wave-scan ----------
// 782 blocks (2x parallelism vs half-pass version); LDS reorder keeps staged
// stores coalesced (runs per bucket). 6 barriers/block vs ~40.

__global__ __launch_bounds__(1024)
void k_bucket(const int* __restrict__ src, const int* __restrict__ dst,
              const float* __restrict__ ea, int* __restrict__ gcur,
              int2* __restrict__ staged, float* __restrict__ params) {
    __shared__ int lcur[NB2];
    __shared__ int lscan[512];
    __shared__ int gbase[NB2];
    __shared__ int wsum[8];
    __shared__ short rbkt[EPB];
    __shared__ int2 recs[EPB];
    int t = threadIdx.x;
    int base = blockIdx.x * EPB;
    float acc = 0.f;
    for (int i = t; i < NB2; i += BTHR) lcur[i] = 0;
    __syncthreads();
    int  myb[EPB / BTHR];
    int  myrank[EPB / BTHR];
    int2 myrec[EPB / BTHR];
#pragma unroll
    for (int i = 0; i < EPB / BTHR; ++i) {
        int e = base + i * BTHR + t;
        myb[i] = -1;
        if (e < N_EDGES) {
            int dv = dst[e];
            float eav = ea[e];
            acc += eav;
            myb[i] = dv >> BSH;
            myrank[i] = atomicAdd(&lcur[myb[i]], 1);
            myrec[i] = make_int2((src[e] << BSH) | (dv & (BNODE - 1)),
                                 __float_as_int(eav));
        }
    }
    __syncthreads();
    // wave-scan of lcur (padded to 512) + per-bucket global reservation
    int v = 0;
    if (t < 512) v = (t < NB2) ? lcur[t] : 0;
    int sv = wscan(v);
    if (t < 512 && (t & 63) == 63) wsum[t >> 6] = sv;
    if (t < NB2 && lcur[t] > 0) gbase[t] = atomicAdd(&gcur[t * GPAD], lcur[t]);
    __syncthreads();
    if (t < 512) {
        int bb = 0;
        for (int i = 0; i < (t >> 6); ++i) bb += wsum[i];
        lscan[t] = sv + bb;                 // inclusive
    }
    __syncthreads();
    // bucket-sorted placement into LDS (exclusive = lscan - lcur)
#pragma unroll
    for (int i = 0; i < EPB / BTHR; ++i) {
        if (myb[i] >= 0) {
            int p = lscan[myb[i]] - lcur[myb[i]] + myrank[i];
            recs[p] = myrec[i];
            rbkt[p] = (short)myb[i];
        }
    }
    __syncthreads();
    int tot = lscan[511];
    for (int p = t; p < tot; p += BTHR) {
        int b = rbkt[p];
        int ex = lscan[b] - lcur[b];
        staged[gbase[b] + (p - ex)] = recs[p];
    }
    for (int m = 32; m >= 1; m >>= 1) acc += __shfl_xor(acc, m, 64);
    __shared__ float sh[BTHR / 64];
    int lane = t & 63, wid = t >> 6;
    if (lane == 0) sh[wid] = acc;
    __syncthreads();
    if (t == 0) {
        float s = 0.f;
        for (int i = 0; i < BTHR / 64; ++i) s += sh[i];
        unsafeAtomicAdd(&params[0], s);
    }
}

// ---------- params precompute + bucket prefix scan ----------

__global__ void k_setup(const float* __restrict__ We1, const float* __restrict__ ae1,
                        const float* __restrict__ We2, const float* __restrict__ ae2,
                        float* __restrict__ params, const int* __restrict__ gcur,
                        int* __restrict__ gstart, int* __restrict__ rowptr) {
    int t = threadIdx.x;
    if (t < 2) {
        float c1 = 0.f, c2 = 0.f;
        for (int c = 0; c < CH; ++c) {
            c1 += We1[t * CH + c] * ae1[t * CH + c];
            c2 += We2[t * CH + c] * ae2[t * CH + c];
        }
        params[2 + t] = c1;
        params[4 + t] = c2;
        if (t == 0) params[1] = params[0] / (float)N_EDGES;
    }
    __shared__ int sh[256];
    int v[2];
    int s = 0;
    for (int j = 0; j < 2; ++j) {
        int i = t * 2 + j;
        v[j] = (i < NB2) ? (gcur[i * GPAD] - i * CAP) : 0;
        s += v[j];
    }
    sh[t] = s;
    __syncthreads();
    for (int off = 1; off < 256; off <<= 1) {
        int u = (t >= off) ? sh[t - off] : 0;
        __syncthreads();
        sh[t] += u;
        __syncthreads();
    }
    int ex = sh[t] - s;
    for (int j = 0; j < 2; ++j) {
        int i = t * 2 + j;
        if (i < NB2) { gstart[i] = ex; ex += v[j]; }
    }
    if (t == 255) {
        gstart[NB2] = N_EDGES;
        rowptr[N_NODES] = N_EDGES;
    }
}

// ---------- pass B: hist + wave-scan, CHUNKED LDS-reorder emission ----------
// Emits split edge arrays: eidx (src<<8|dstlow, 4B) + eea (fp16 ea, 2B).

__global__ __launch_bounds__(1024)
void k_scatter(const int2* __restrict__ staged, const int* __restrict__ gcur,
               const int* __restrict__ gstart,
               int* __restrict__ rowptr, int* __restrict__ eidx,
               __half* __restrict__ eea) {
    __shared__ int cntl[BNODE];
    __shared__ int cur[BNODE];
    __shared__ int cchist[BNODE];
    __shared__ int cexcl[BNODE];
    __shared__ int ws4[4];
    __shared__ short rbkt[CHK];
    __shared__ int2 recs[CHK];
    int b = blockIdx.x, t = threadIdx.x;
    int nbase = b << BSH;
    int bcount = N_NODES - nbase;
    if (bcount > BNODE) bcount = BNODE;
    int sbase = b * CAP;
    int en = gcur[b * GPAD];
    int st_true = gstart[b];
    if (t < BNODE) cntl[t] = 0;
    __syncthreads();
    for (int e = sbase + t; e < en; e += 1024)
        atomicAdd(&cntl[staged[e].x & (BNODE - 1)], 1);
    __syncthreads();
    {   // wave-scan cntl -> exclusive global start per node
        int v = (t < BNODE) ? cntl[t] : 0;
        int sv = wscan(v);
        if (t < BNODE && (t & 63) == 63) ws4[t >> 6] = sv;
        __syncthreads();
        if (t < BNODE) {
            int bb = 0;
            for (int i = 0; i < (t >> 6); ++i) bb += ws4[i];
            int ex = st_true + sv + bb - v;   // exclusive, global
            cur[t] = ex;
            if (t < bcount) rowptr[nbase + t] = ex;
        }
        __syncthreads();
    }
    int count = en - sbase;
    for (int cb = 0; cb < count; cb += CHK) {
        int clen = count - cb;
        if (clen > CHK) clen = CHK;
        if (t < BNODE) cchist[t] = 0;
        __syncthreads();
        int  mylo[CHK / 1024];
        int  myrank[CHK / 1024];
        int2 myrec[CHK / 1024];
#pragma unroll
        for (int i = 0; i < CHK / 1024; ++i) {
            int p = i * 1024 + t;
            mylo[i] = -1;
            if (p < clen) {
                int2 r = staged[sbase + cb + p];   // second read: L2-hot window
                mylo[i] = r.x & (BNODE - 1);
                myrank[i] = atomicAdd(&cchist[mylo[i]], 1);
                myrec[i] = r;
            }
        }
        __syncthreads();
        {   // wave-scan cchist -> cexcl (exclusive within chunk)
            int v = (t < BNODE) ? cchist[t] : 0;
            int sv = wscan(v);
            if (t < BNODE && (t & 63) == 63) ws4[t >> 6] = sv;
            __syncthreads();
            if (t < BNODE) {
                int bb = 0;
                for (int i = 0; i < (t >> 6); ++i) bb += ws4[i];
                cexcl[t] = sv + bb - v;
            }
            __syncthreads();
        }
#pragma unroll
        for (int i = 0; i < CHK / 1024; ++i) {
            if (mylo[i] >= 0) {
                int p = cexcl[mylo[i]] + myrank[i];
                recs[p] = myrec[i];
                rbkt[p] = (short)mylo[i];
            }
        }
        __syncthreads();
        for (int p = t; p < clen; p += 1024) {
            int lo = rbkt[p];
            int pos = cur[lo] + (p - cexcl[lo]);
            int2 r = recs[p];
            eidx[pos] = r.x;
            eea[pos] = __float2half(__int_as_float(r.y));
        }
        __syncthreads();
        if (t < BNODE) cur[t] += cchist[t];
        __syncthreads();
    }
}

// ---------- dense: h = x @ W (LDS-tiled), fp16 h-table out + fp32 asrc/adst ----------

#define COLS(ac, xv)                                                     \
    ac[0] = fmaf(xv.x, w0.x, ac[0]); ac[1] = fmaf(xv.x, w0.y, ac[1]);    \
    ac[2] = fmaf(xv.x, w0.z, ac[2]); ac[3] = fmaf(xv.x, w0.w, ac[3]);    \
    ac[0] = fmaf(xv.y, w1.x, ac[0]); ac[1] = fmaf(xv.y, w1.y, ac[1]);    \
    ac[2] = fmaf(xv.y, w1.z, ac[2]); ac[3] = fmaf(xv.y, w1.w, ac[3]);    \
    ac[0] = fmaf(xv.z, w2.x, ac[0]); ac[1] = fmaf(xv.z, w2.y, ac[1]);    \
    ac[2] = fmaf(xv.z, w2.z, ac[2]); ac[3] = fmaf(xv.z, w2.w, ac[3]);    \
    ac[0] = fmaf(xv.w, w3.x, ac[0]); ac[1] = fmaf(xv.w, w3.y, ac[1]);    \
    ac[2] = fmaf(xv.w, w3.z, ac[2]); ac[3] = fmaf(xv.w, w3.w, ac[3]);

template <int FIN>
__global__ __launch_bounds__(256)
void k_linear(const float* __restrict__ x, const float* __restrict__ W,
              const float* __restrict__ a_src, const float* __restrict__ a_dst,
              __half* __restrict__ h16, float* __restrict__ asrc,
              float* __restrict__ adst) {
    constexpr int PAD = FIN + 4;
    __shared__ float ws[FIN * HC];
    __shared__ float xs[64 * PAD];
    int t = threadIdx.x;
    int nbase = blockIdx.x * 64;
    int bcount = N_NODES - nbase;
    if (bcount > 64) bcount = 64;

    for (int i = t; i < FIN * HC / 4; i += 256)
        ((float4*)ws)[i] = ((const float4*)W)[i];
    const float4* xg = (const float4*)(x + (size_t)nbase * FIN);
    int nf4 = bcount * FIN / 4;
    for (int i = t; i < 64 * FIN / 4; i += 256) {
        if (i < nf4) {
            float4 v = xg[i];
            int flat = i * 4;
            int row = flat / FIN, col = flat % FIN;
            *(float4*)&xs[row * PAD + col] = v;
        }
    }
    __syncthreads();

    int cg = t & 7, np = t >> 3;
    int n0 = np * 2, n1 = n0 + 1;
    float acc0[4] = {0.f, 0.f, 0.f, 0.f};
    float acc1[4] = {0.f, 0.f, 0.f, 0.f};
#pragma unroll
    for (int k = 0; k < FIN; k += 4) {
        float4 xa = *(const float4*)&xs[n0 * PAD + k];
        float4 xb = *(const float4*)&xs[n1 * PAD + k];
        const float4* wp = (const float4*)&ws[k * HC] + cg;
        float4 w0 = wp[0], w1 = wp[8], w2 = wp[16], w3 = wp[24];
        COLS(acc0, xa)
        COLS(acc1, xb)
    }

    int hh = cg >> 2;
    float s0 = 0.f, d0 = 0.f, s1 = 0.f, d1 = 0.f;
#pragma unroll
    for (int j = 0; j < 4; ++j) {
        float av = a_src[hh * CH + (cg & 3) * 4 + j];
        float dv = a_dst[hh * CH + (cg & 3) * 4 + j];
        s0 = fmaf(acc0[j], av, s0); d0 = fmaf(acc0[j], dv, d0);
        s1 = fmaf(acc1[j], av, s1); d1 = fmaf(acc1[j], dv, d1);
    }
    s0 += __shfl_xor(s0, 1, 64); s0 += __shfl_xor(s0, 2, 64);
    d0 += __shfl_xor(d0, 1, 64); d0 += __shfl_xor(d0, 2, 64);
    s1 += __shfl_xor(s1, 1, 64); s1 += __shfl_xor(s1, 2, 64);
    d1 += __shfl_xor(d1, 1, 64); d1 += __shfl_xor(d1, 2, 64);

    if (n0 < bcount) {
        __half2 pa = __floats2half2_rn(acc0[0], acc0[1]);
        __half2 pb = __floats2half2_rn(acc0[2], acc0[3]);
        *(uint2*)&h16[(size_t)(nbase + n0) * HC + cg * 4] =
            make_uint2(*(unsigned*)&pa, *(unsigned*)&pb);
        if ((cg & 3) == 0) {
            asrc[(nbase + n0) * 2 + hh] = s0;
            adst[(nbase + n0) * 2 + hh] = d0;
        }
    }
    if (n1 < bcount) {
        __half2 pa = __floats2half2_rn(acc1[0], acc1[1]);
        __half2 pb = __floats2half2_rn(acc1[2], acc1[3]);
        *(uint2*)&h16[(size_t)(nbase + n1) * HC + cg * 4] =
            make_uint2(*(unsigned*)&pa, *(unsigned*)&pb);
        if ((cg & 3) == 0) {
            asrc[(nbase + n1) * 2 + hh] = s1;
            adst[(nbase + n1) * 2 + hh] = d1;
        }
    }
}

// ---------- fused GAT layer: 16 lanes/node, fp16 h gathers, split edge arrays ----------

#define FMA4(ACC, WGT, VEC)                                                      \
    ACC.x = fmaf(WGT, VEC.x, ACC.x); ACC.y = fmaf(WGT, VEC.y, ACC.y);            \
    ACC.z = fmaf(WGT, VEC.z, ACC.z); ACC.w = fmaf(WGT, VEC.w, ACC.w);

__device__ __forceinline__ void unpack8(uint4 hv, float4& p, float4& u) {
    float2 f0 = __half22float2(*(__half2*)&hv.x);
    float2 f1 = __half22float2(*(__half2*)&hv.y);
    float2 f2 = __half22float2(*(__half2*)&hv.z);
    float2 f3 = __half22float2(*(__half2*)&hv.w);
    p = make_float4(f0.x, f0.y, f1.x, f1.y);
    u = make_float4(f2.x, f2.y, f3.x, f3.y);
}

template <int FUSE>
__global__ __launch_bounds__(256)
void k_gat(const int* __restrict__ rowptr, const int* __restrict__ eidx,
           const __half* __restrict__ eea, const __half* __restrict__ h16,
           const float* __restrict__ asrc, const float* __restrict__ adst,
           const float* __restrict__ params, int ceoff,
           const float* __restrict__ bias, int do_relu,
           float* __restrict__ outf, __half* __restrict__ outh,
           const float* __restrict__ W2,
           const float* __restrict__ as2, const float* __restrict__ ad2,
           float* __restrict__ asrc2, float* __restrict__ adst2) {
    __shared__ float w2s[FUSE ? HC * HC : 4];
    int t = threadIdx.x;
    if (FUSE) {
        for (int i = t; i < HC * HC / 4; i += 256)
            ((float4*)w2s)[i] = ((const float4*)W2)[i];
        __syncthreads();
    }
    int tid = blockIdx.x * blockDim.x + t;
    int n = tid >> 4;
    if (n >= N_NODES) return;
    int q = tid & 15;
    int chan = q & 3, quarter = q >> 2, hh = chan >> 1;
    int st = rowptr[n], en = rowptr[n + 1];
    int len = en - st;
    int q0 = st + ((len * quarter) >> 2);
    int q1 = st + ((len * (quarter + 1)) >> 2);
    float ce = params[ceoff + hh];
    float adn = adst[n * 2 + hh];
    const uint4* h4v = (const uint4*)h16;     // one uint4 = 8 halfs = this lane's channels
    float4 A0 = make_float4(0.f, 0.f, 0.f, 0.f);
    float4 A1 = make_float4(0.f, 0.f, 0.f, 0.f);
    float ssum = 0.f;
    for (int e = q0; e < q1; e += 4) {
        int e1 = e + 1, e2 = e + 2, e3 = e + 3;
        int i1 = e1 < q1 ? e1 : q1 - 1;
        int i2 = e2 < q1 ? e2 : q1 - 1;
        int i3 = e3 < q1 ? e3 : q1 - 1;
        int r0 = eidx[e], r1 = eidx[i1], r2 = eidx[i2], r3 = eidx[i3];
        float ea0 = __half2float(eea[e]),  ea1 = __half2float(eea[i1]);
        float ea2 = __half2float(eea[i2]), ea3 = __half2float(eea[i3]);
        int s0 = r0 >> BSH, s1 = r1 >> BSH, s2 = r2 >> BSH, s3 = r3 >> BSH;
        float a0 = asrc[s0 * 2 + hh], a1 = asrc[s1 * 2 + hh];
        float a2 = asrc[s2 * 2 + hh], a3 = asrc[s3 * 2 + hh];
        uint4 hv0 = h4v[s0 * 4 + chan];
        uint4 hv1 = h4v[s1 * 4 + chan];
        uint4 hv2 = h4v[s2 * 4 + chan];
        uint4 hv3 = h4v[s3 * 4 + chan];
        float g0 = __expf(lrelu(a0 + adn + ce * ea0));
        float g1 = __expf(lrelu(a1 + adn + ce * ea1));
        float g2 = __expf(lrelu(a2 + adn + ce * ea2));
        float g3 = __expf(lrelu(a3 + adn + ce * ea3));
        g1 = (e1 < q1) ? g1 : 0.f;
        g2 = (e2 < q1) ? g2 : 0.f;
        g3 = (e3 < q1) ? g3 : 0.f;
        float4 p0, u0, p1, u1, p2, u2, p3, u3;
        unpack8(hv0, p0, u0); unpack8(hv1, p1, u1);
        unpack8(hv2, p2, u2); unpack8(hv3, p3, u3);
        FMA4(A0, g0, p0) FMA4(A1, g0, u0) ssum += g0;
        FMA4(A0, g1, p1) FMA4(A1, g1, u1) ssum += g1;
        FMA4(A0, g2, p2) FMA4(A1, g2, u2) ssum += g2;
        FMA4(A0, g3, p3) FMA4(A1, g3, u3) ssum += g3;
    }
    if (quarter == 0) {
        // self-loop (eattr = mean) counted once, in quarter 0
        float gself = __expf(lrelu(asrc[n * 2 + hh] + adn + ce * params[1]));
        float4 psf, usf;
        unpack8(h4v[n * 4 + chan], psf, usf);
        FMA4(A0, gself, psf) FMA4(A1, gself, usf)
        ssum += gself;
    }
    // merge the four edge-quarters: partner lanes tid^4 then tid^8 (same wave)
    A0.x += __shfl_xor(A0.x, 4, 64); A0.y += __shfl_xor(A0.y, 4, 64);
    A0.z += __shfl_xor(A0.z, 4, 64); A0.w += __shfl_xor(A0.w, 4, 64);
    A1.x += __shfl_xor(A1.x, 4, 64); A1.y += __shfl_xor(A1.y, 4, 64);
    A1.z += __shfl_xor(A1.z, 4, 64); A1.w += __shfl_xor(A1.w, 4, 64);
    ssum += __shfl_xor(ssum, 4, 64);
    A0.x += __shfl_xor(A0.x, 8, 64); A0.y += __shfl_xor(A0.y, 8, 64);
    A0.z += __shfl_xor(A0.z, 8, 64); A0.w += __shfl_xor(A0.w, 8, 64);
    A1.x += __shfl_xor(A1.x, 8, 64); A1.y += __shfl_xor(A1.y, 8, 64);
    A1.z += __shfl_xor(A1.z, 8, 64); A1.w += __shfl_xor(A1.w, 8, 64);
    ssum += __shfl_xor(ssum, 8, 64);
    if (quarter != 0) return;
    float inv = 1.f / (ssum + 1e-16f);
    int b4 = chan * 2;
    float4 bv0 = ((const float4*)bias)[b4], bv1 = ((const float4*)bias)[b4 + 1];
    float4 v0 = make_float4(A0.x * inv + bv0.x, A0.y * inv + bv0.y,
                            A0.z * inv + bv0.z, A0.w * inv + bv0.w);
    float4 v1 = make_float4(A1.x * inv + bv1.x, A1.y * inv + bv1.y,
                            A1.z * inv + bv1.z, A1.w * inv + bv1.w);
    if (do_relu) {
        v0.x = fmaxf(v0.x, 0.f); v0.y = fmaxf(v0.y, 0.f);
        v0.z = fmaxf(v0.z, 0.f); v0.w = fmaxf(v0.w, 0.f);
        v1.x = fmaxf(v1.x, 0.f); v1.y = fmaxf(v1.y, 0.f);
        v1.z = fmaxf(v1.z, 0.f); v1.w = fmaxf(v1.w, 0.f);
    }
    if (!FUSE) {
        ((float4*)outf)[n * 8 + b4] = v0;
        ((float4*)outf)[n * 8 + b4 + 1] = v1;
        return;
    }
    // ---- fused layer-2 linear (fp32): h2 = v @ W2; chan lanes hold full row ----
    int lane = t & 63;
    int bse = lane & 48;                  // node-group lane base (quarter-0 chan lanes)
    float h2[8] = {0.f, 0.f, 0.f, 0.f, 0.f, 0.f, 0.f, 0.f};
#pragma unroll
    for (int cc = 0; cc < 4; ++cc) {
        int sl = bse | cc;
        float vv[8];
        vv[0] = __shfl(v0.x, sl, 64); vv[1] = __shfl(v0.y, sl, 64);
        vv[2] = __shfl(v0.z, sl, 64); vv[3] = __shfl(v0.w, sl, 64);
        vv[4] = __shfl(v1.x, sl, 64); vv[5] = __shfl(v1.y, sl, 64);
        vv[6] = __shfl(v1.z, sl, 64); vv[7] = __shfl(v1.w, sl, 64);
#pragma unroll
        for (int m = 0; m < 8; ++m) {      // k ascending (== k_linear order)
            const float* wrow = &w2s[(cc * 8 + m) * HC + chan * 8];
            float4 wa = *(const float4*)&wrow[0];
            float4 wb = *(const float4*)&wrow[4];
            h2[0] = fmaf(vv[m], wa.x, h2[0]); h2[1] = fmaf(vv[m], wa.y, h2[1]);
            h2[2] = fmaf(vv[m], wa.z, h2[2]); h2[3] = fmaf(vv[m], wa.w, h2[3]);
            h2[4] = fmaf(vv[m], wb.x, h2[4]); h2[5] = fmaf(vv[m], wb.y, h2[5]);
            h2[6] = fmaf(vv[m], wb.z, h2[6]); h2[7] = fmaf(vv[m], wb.w, h2[7]);
        }
    }
    __half2 q0h = __floats2half2_rn(h2[0], h2[1]);
    __half2 q1h = __floats2half2_rn(h2[2], h2[3]);
    __half2 q2h = __floats2half2_rn(h2[4], h2[5]);
    __half2 q3h = __floats2half2_rn(h2[6], h2[7]);
    *(uint4*)&outh[(size_t)n * HC + chan * 8] =
        make_uint4(*(unsigned*)&q0h, *(unsigned*)&q1h,
                   *(unsigned*)&q2h, *(unsigned*)&q3h);
    float s2 = 0.f, d2 = 0.f;
#pragma unroll
    for (int j = 0; j < 8; ++j) {
        s2 = fmaf(h2[j], as2[chan * 8 + j], s2);
        d2 = fmaf(h2[j], ad2[chan * 8 + j], d2);
    }
    s2 += __shfl_xor(s2, 1, 64);           // chan0+1 = head0, chan2+3 = head1
    d2 += __shfl_xor(d2, 1, 64);
    if ((chan & 1) == 0) {
        asrc2[n * 2 + (chan >> 1)] = s2;
        adst2[n * 2 + (chan >> 1)] = d2;
    }
}

// ---------- pooling stage 1: streaming per-graph partial sums ----------

__global__ __launch_bounds__(1024)
void k_pool1(const float* __restrict__ feat, const int* __restrict__ batch,
             float* __restrict__ gsums) {
    __shared__ float gsum[GSPAN][32];
    int t = threadIdx.x;
    int c = t & 31, r = t >> 5;     // r in 0..31, 16 nodes each
    int base = blockIdx.x * NPB;
    if (t < GSPAN * 32) ((float*)gsum)[t] = 0.f;
    __syncthreads();
    int g0 = batch[base];
    float acc = 0.f;
    int gprev = -1;
    for (int i = 0; i < NPB / 32; ++i) {
        int n = base + r * (NPB / 32) + i;
        if (n >= N_NODES) break;
        int g = batch[n] - g0;
        if (g != gprev) {
            if (gprev >= 0) {
                if (gprev < GSPAN) atomicAdd(&gsum[gprev][c], acc);
                else unsafeAtomicAdd(&gsums[(g0 + gprev) * 32 + c], acc);
            }
            acc = 0.f;
            gprev = g;
        }
        acc += feat[(size_t)n * HC + c];
    }
    if (gprev >= 0) {
        if (gprev < GSPAN) atomicAdd(&gsum[gprev][c], acc);
        else unsafeAtomicAdd(&gsums[(g0 + gprev) * 32 + c], acc);
    }
    __syncthreads();
    if (t < GSPAN * 32) {
        int gi = t >> 5, cc = t & 31;
        float v = gsum[gi][cc];
        if (v != 0.f && g0 + gi < NGRAPH)
            unsafeAtomicAdd(&gsums[(g0 + gi) * 32 + cc], v);
    }
}

// ---------- pooling stage 2: mean + MLP head (tiny) ----------

__global__ void k_mlp(const float* __restrict__ gsums, const int* __restrict__ batch,
                      const float* __restrict__ Wf1, const float* __restrict__ bf1,
                      const float* __restrict__ Wf2, const float* __restrict__ bf2,
                      float* __restrict__ out) {
    int g = blockIdx.x;
    __shared__ int sse[2];
    __shared__ float emb[32];
    __shared__ float hid[32];
    if (threadIdx.x < 2) {
        int target = g + (int)threadIdx.x;
        int lo = 0, hi = N_NODES;
        while (lo < hi) {
            int mid = (lo + hi) >> 1;
            if (batch[mid] < target) lo = mid + 1; else hi = mid;
        }
        sse[threadIdx.x] = lo;
    }
    __syncthreads();
    int cnt = sse[1] - sse[0];
    if (threadIdx.x < 32)
        emb[threadIdx.x] = gsums[g * 32 + threadIdx.x] / (float)(cnt > 0 ? cnt : 1);
    __syncthreads();
    if (threadIdx.x < 32) {
        int j = threadIdx.x;
        float a = bf1[j];
        for (int k = 0; k < 32; ++k) a = fmaf(emb[k], Wf1[k * 32 + j], a);
        hid[j] = fmaxf(a, 0.f);
    }
    __syncthreads();
    if (threadIdx.x < 2) {
        int j = threadIdx.x;
        float o = bf2[j];
        for (int k = 0; k < 32; ++k) o = fmaf(hid[k], Wf2[k * 2 + j], o);
        out[g * 2 + j] = o;
    }
}

extern "C" void kernel_launch(void* const* d_in, const int* in_sizes, int n_in,
                              void* d_out, int out_size, void* d_ws, size_t ws_size,
                              hipStream_t stream) {
    const float* x   = (const float*)d_in[0];
    const int*   ei  = (const int*)d_in[1];
    const float* ea  = (const float*)d_in[2];
    const int* batch = (const int*)d_in[3];
    const float* W1  = (const float*)d_in[4];
    const float* as1 = (const float*)d_in[5];
    const float* ad1 = (const float*)d_in[6];
    const float* We1 = (const float*)d_in[7];
    const float* ae1 = (const float*)d_in[8];
    const float* b1  = (const float*)d_in[9];
    const float* W2  = (const float*)d_in[10];
    const float* as2 = (const float*)d_in[11];
    const float* ad2 = (const float*)d_in[12];
    const float* We2 = (const float*)d_in[13];
    const float* ae2 = (const float*)d_in[14];
    const float* b2  = (const float*)d_in[15];
    const float* Wf1 = (const float*)d_in[16];
    const float* bf1 = (const float*)d_in[17];
    const float* Wf2 = (const float*)d_in[18];
    const float* bf2 = (const float*)d_in[19];
    float* out = (float*)d_out;
    (void)in_sizes; (void)n_in; (void)out_size; (void)ws_size;

    const int* srcp = ei;
    const int* dstp = ei + N_EDGES;

    char* wsb = (char*)d_ws;
    size_t off = 0;
    auto alloc = [&](size_t bytes) -> char* {
        char* p = wsb + off;
        off = (off + bytes + 255) & ~(size_t)255;
        return p;
    };
    float* params = (float*)alloc(64);
    // region A: staged (28.8 MB); reused after k_scatter as fp32 final-feature buf
    char* regA = alloc((size_t)NB2 * CAP * 8 + 4096);
    int2*  staged = (int2*)regA;
    float* feat   = (float*)regA;
    int*   eidx   = (int*)alloc((size_t)N_EDGES * 4);
    __half* eea   = (__half*)alloc((size_t)N_EDGES * 2);
    __half* h16a  = (__half*)alloc((size_t)N_NODES * HC * 2);
    __half* h16b  = (__half*)alloc((size_t)N_NODES * HC * 2);
    float* asrc   = (float*)alloc((size_t)N_NODES * 2 * 4);
    float* adst   = (float*)alloc((size_t)N_NODES * 2 * 4);
    float* asrc2  = (float*)alloc((size_t)N_NODES * 2 * 4);
    float* adst2  = (float*)alloc((size_t)N_NODES * 2 * 4);
    int*   gstart = (int*)alloc((size_t)(NB2 + 1) * 4);
    int*   gcur   = (int*)alloc((size_t)NB2 * GPAD * 4);
    int*   rowptr = (int*)alloc((size_t)(N_NODES + 1) * 4);
    float* gsums  = (float*)alloc((size_t)NGRAPH * HC * 4);

    const int nBlkB = (N_EDGES + EPB - 1) / EPB;                // 782
    const int nBlkL = (N_NODES + 63) / 64;                      // 1563
    const int nBlkG = (N_NODES * 16 + 255) / 256;               // 6250
    const int nBlkP = (N_NODES + NPB - 1) / NPB;                // 196

    // fixed-capacity bucket sort (no pre-histogram pass)
    k_init<<<1, 1024, 0, stream>>>(gcur, params, gsums);
    k_bucket<<<nBlkB, BTHR, 0, stream>>>(srcp, dstp, ea, gcur, staged, params);
    k_setup<<<1, 256, 0, stream>>>(We1, ae1, We2, ae2, params, gcur, gstart, rowptr);
    k_scatter<<<NB2, 1024, 0, stream>>>(staged, gcur, gstart, rowptr, eidx, eea);

    // ----- layer 1 (+ fused layer-2 linear in epilogue, fp16 tables) -----
    k_linear<F_IN><<<nBlkL, 256, 0, stream>>>(x, W1, as1, ad1, h16a, asrc, adst);
    k_gat<1><<<nBlkG, 256, 0, stream>>>(rowptr, eidx, eea, h16a, asrc, adst, params, 2, b1, 1,
                                        nullptr, h16b, W2, as2, ad2, asrc2, adst2);

    // ----- layer 2 (reads fp16 h2; writes fp32 features into staged region) -----
    k_gat<0><<<nBlkG, 256, 0, stream>>>(rowptr, eidx, eea, h16b, asrc2, adst2, params, 4, b2, 0,
                                        feat, nullptr, W2, as2, ad2, asrc2, adst2);

    // ----- pool (streaming partials) + MLP head -----
    k_pool1<<<nBlkP, 1024, 0, stream>>>(feat, batch, gsums);
    k_mlp<<<NGRAPH, 64, 0, stream>>>(gsums, batch, Wf1, bf1, Wf2, bf2, out);
}

// Round 11
// 323.040 us; speedup vs baseline: 1.3119x; 1.0340x over previous
//
#include <hip/hip_runtime.h>
#include <hip/hip_fp16.h>

#define N_NODES 100000
#define N_EDGES 3200000
#define F_IN    128
#define HC      32      // H*C
#define CH      16      // C per head
#define NGRAPH  64
#define NEG     0.2f

#define BSH   8                                   // 256 nodes per bucket
#define BNODE (1 << BSH)
#define NB2   ((N_NODES + BNODE - 1) >> BSH)      // 391 buckets
#define CAP   9216                                // fixed staged slot per bucket (= 9*1024)
#define EPB   4096                                // edges per k_bucket block (single pass)
#define BTHR  1024                                // k_bucket threads
#define GPAD  16                                  // gcur stride (1 line/bucket)
#define NPB   512                                 // nodes per k_pool1 block
#define GSPAN 16                                  // max graphs spanned per pool block (LDS bins)

__device__ __forceinline__ float lrelu(float x) { return x > 0.f ? x : NEG * x; }

// inclusive scan over the 64-lane wave
__device__ __forceinline__ int wscan(int v) {
#pragma unroll
    for (int off = 1; off < 64; off <<= 1) {
        int u = __shfl_up(v, off, 64);
        if ((int)(threadIdx.x & 63) >= off) v += u;
    }
    return v;
}

// ---------- init: fixed bucket bases + params + gsums zero ----------

__global__ void k_init(int* __restrict__ gcur, float* __restrict__ params,
                       float* __restrict__ gsums) {
    int t = threadIdx.x;
    if (t < NB2) gcur[t * GPAD] = t * CAP;
    if (t < 16) params[t] = 0.f;
    gsums[t] = 0.f;                 // 1024 threads
    gsums[t + 1024] = 0.f;          // total 2048 = NGRAPH*HC
}

// ---------- pass A: bucket scatter, single 4096-edge pass, wave-scan ----------
// Emits SPLIT staged arrays (sidx 4B + sea fp16 2B): 19.2 MB written vs 25.6.
// LDS reorder keeps stores coalesced (runs per bucket).

__global__ __launch_bounds__(1024)
void k_bucket(const int* __restrict__ src, const int* __restrict__ dst,
              const float* __restrict__ ea, int* __restrict__ gcur,
              int* __restrict__ sidx, __half* __restrict__ sea,
              float* __restrict__ params) {
    __shared__ int lcur[NB2];
    __shared__ int lscan[512];
    __shared__ int gbase[NB2];
    __shared__ int wsum[8];
    __shared__ short rbkt[EPB];
    __shared__ int ridx[EPB];
    __shared__ __half rea[EPB];
    int t = threadIdx.x;
    int base = blockIdx.x * EPB;
    float acc = 0.f;
    for (int i = t; i < NB2; i += BTHR) lcur[i] = 0;
    __syncthreads();
    int   myb[EPB / BTHR];
    int   myrank[EPB / BTHR];
    int   myidx[EPB / BTHR];
    float myea[EPB / BTHR];
#pragma unroll
    for (int i = 0; i < EPB / BTHR; ++i) {
        int e = base + i * BTHR + t;
        myb[i] = -1;
        if (e < N_EDGES) {
            int dv = dst[e];
            float eav = ea[e];
            acc += eav;
            myb[i] = dv >> BSH;
            myrank[i] = atomicAdd(&lcur[myb[i]], 1);
            myidx[i] = (src[e] << BSH) | (dv & (BNODE - 1));
            myea[i] = eav;
        }
    }
    __syncthreads();
    // wave-scan of lcur (padded to 512) + per-bucket global reservation
    int v = 0;
    if (t < 512) v = (t < NB2) ? lcur[t] : 0;
    int sv = wscan(v);
    if (t < 512 && (t & 63) == 63) wsum[t >> 6] = sv;
    if (t < NB2 && lcur[t] > 0) gbase[t] = atomicAdd(&gcur[t * GPAD], lcur[t]);
    __syncthreads();
    if (t < 512) {
        int bb = 0;
        for (int i = 0; i < (t >> 6); ++i) bb += wsum[i];
        lscan[t] = sv + bb;                 // inclusive
    }
    __syncthreads();
    // bucket-sorted placement into LDS (exclusive = lscan - lcur)
#pragma unroll
    for (int i = 0; i < EPB / BTHR; ++i) {
        if (myb[i] >= 0) {
            int p = lscan[myb[i]] - lcur[myb[i]] + myrank[i];
            ridx[p] = myidx[i];
            rea[p] = __float2half(myea[i]);
            rbkt[p] = (short)myb[i];
        }
    }
    __syncthreads();
    int tot = lscan[511];
    for (int p = t; p < tot; p += BTHR) {
        int b = rbkt[p];
        int ex = lscan[b] - lcur[b];
        int gpos = gbase[b] + (p - ex);
        sidx[gpos] = ridx[p];
        sea[gpos] = rea[p];
    }
    for (int m = 32; m >= 1; m >>= 1) acc += __shfl_xor(acc, m, 64);
    __shared__ float sh[BTHR / 64];
    int lane = t & 63, wid = t >> 6;
    if (lane == 0) sh[wid] = acc;
    __syncthreads();
    if (t == 0) {
        float s = 0.f;
        for (int i = 0; i < BTHR / 64; ++i) s += sh[i];
        unsafeAtomicAdd(&params[0], s);
    }
}

// ---------- params precompute + bucket prefix scan ----------

__global__ void k_setup(const float* __restrict__ We1, const float* __restrict__ ae1,
                        const float* __restrict__ We2, const float* __restrict__ ae2,
                        float* __restrict__ params, const int* __restrict__ gcur,
                        int* __restrict__ gstart, int* __restrict__ rowptr) {
    int t = threadIdx.x;
    if (t < 2) {
        float c1 = 0.f, c2 = 0.f;
        for (int c = 0; c < CH; ++c) {
            c1 += We1[t * CH + c] * ae1[t * CH + c];
            c2 += We2[t * CH + c] * ae2[t * CH + c];
        }
        params[2 + t] = c1;
        params[4 + t] = c2;
        if (t == 0) params[1] = params[0] / (float)N_EDGES;
    }
    __shared__ int sh[256];
    int v[2];
    int s = 0;
    for (int j = 0; j < 2; ++j) {
        int i = t * 2 + j;
        v[j] = (i < NB2) ? (gcur[i * GPAD] - i * CAP) : 0;
        s += v[j];
    }
    sh[t] = s;
    __syncthreads();
    for (int off = 1; off < 256; off <<= 1) {
        int u = (t >= off) ? sh[t - off] : 0;
        __syncthreads();
        sh[t] += u;
        __syncthreads();
    }
    int ex = sh[t] - s;
    for (int j = 0; j < 2; ++j) {
        int i = t * 2 + j;
        if (i < NB2) { gstart[i] = ex; ex += v[j]; }
    }
    if (t == 255) {
        gstart[NB2] = N_EDGES;
        rowptr[N_NODES] = N_EDGES;
    }
}

// ---------- pass B: SINGLE-READ register-resident sort within bucket ----------
// Each thread holds its 9 staged records in registers (static unroll, no spill);
// hist from regs -> wave-scan -> node-sorted placement into full-bucket LDS ->
// CONTIGUOUS coalesced emission (epack positions are [st_true, st_true+count)).
// 56 KB LDS, 2 blocks/CU, all 391 blocks co-resident; 4 barriers total.

__global__ __launch_bounds__(1024)
void k_scatter(const int* __restrict__ sidx, const __half* __restrict__ sea,
               const int* __restrict__ gcur, const int* __restrict__ gstart,
               int* __restrict__ rowptr, int* __restrict__ eidx,
               __half* __restrict__ eea) {
    __shared__ int cntl[BNODE];
    __shared__ int excl[BNODE];
    __shared__ int ws4[4];
    __shared__ int lidx[CAP];
    __shared__ __half lea[CAP];
    int b = blockIdx.x, t = threadIdx.x;
    int nbase = b << BSH;
    int bcount = N_NODES - nbase;
    if (bcount > BNODE) bcount = BNODE;
    int sbase = b * CAP;
    int en = gcur[b * GPAD];
    int count = en - sbase;
    int st_true = gstart[b];
    if (t < BNODE) cntl[t] = 0;
    __syncthreads();
    int    myidx[CAP / BTHR];     // 9
    __half myea[CAP / BTHR];
    int    myrank[CAP / BTHR];
#pragma unroll
    for (int i = 0; i < CAP / BTHR; ++i) {
        int p = i * BTHR + t;
        myrank[i] = -1;
        if (p < count) {
            myidx[i] = sidx[sbase + p];
            myea[i] = sea[sbase + p];
            myrank[i] = atomicAdd(&cntl[myidx[i] & (BNODE - 1)], 1);
        }
    }
    __syncthreads();
    {   // wave-scan cntl -> exclusive local start per node, write rowptr
        int v = (t < BNODE) ? cntl[t] : 0;
        int sv = wscan(v);
        if (t < BNODE && (t & 63) == 63) ws4[t >> 6] = sv;
        __syncthreads();
        if (t < BNODE) {
            int bb = 0;
            for (int i = 0; i < (t >> 6); ++i) bb += ws4[i];
            int ex = sv + bb - v;             // local exclusive
            excl[t] = ex;
            if (t < bcount) rowptr[nbase + t] = st_true + ex;
        }
        __syncthreads();
    }
#pragma unroll
    for (int i = 0; i < CAP / BTHR; ++i) {
        if (myrank[i] >= 0) {
            int lo = myidx[i] & (BNODE - 1);
            int p = excl[lo] + myrank[i];
            lidx[p] = myidx[i];
            lea[p] = myea[i];
        }
    }
    __syncthreads();
    for (int p = t; p < count; p += BTHR) {
        eidx[st_true + p] = lidx[p];
        eea[st_true + p] = lea[p];
    }
}

// ---------- dense: h = x @ W (LDS-tiled), fp16 h-table out + fp32 asrc/adst ----------

#define COLS(ac, xv)                                                     \
    ac[0] = fmaf(xv.x, w0.x, ac[0]); ac[1] = fmaf(xv.x, w0.y, ac[1]);    \
    ac[2] = fmaf(xv.x, w0.z, ac[2]); ac[3] = fmaf(xv.x, w0.w, ac[3]);    \
    ac[0] = fmaf(xv.y, w1.x, ac[0]); ac[1] = fmaf(xv.y, w1.y, ac[1]);    \
    ac[2] = fmaf(xv.y, w1.z, ac[2]); ac[3] = fmaf(xv.y, w1.w, ac[3]);    \
    ac[0] = fmaf(xv.z, w2.x, ac[0]); ac[1] = fmaf(xv.z, w2.y, ac[1]);    \
    ac[2] = fmaf(xv.z, w2.z, ac[2]); ac[3] = fmaf(xv.z, w2.w, ac[3]);    \
    ac[0] = fmaf(xv.w, w3.x, ac[0]); ac[1] = fmaf(xv.w, w3.y, ac[1]);    \
    ac[2] = fmaf(xv.w, w3.z, ac[2]); ac[3] = fmaf(xv.w, w3.w, ac[3]);

template <int FIN>
__global__ __launch_bounds__(256)
void k_linear(const float* __restrict__ x, const float* __restrict__ W,
              const float* __restrict__ a_src, const float* __restrict__ a_dst,
              __half* __restrict__ h16, float* __restrict__ asrc,
              float* __restrict__ adst) {
    constexpr int PAD = FIN + 4;
    __shared__ float ws[FIN * HC];
    __shared__ float xs[64 * PAD];
    int t = threadIdx.x;
    int nbase = blockIdx.x * 64;
    int bcount = N_NODES - nbase;
    if (bcount > 64) bcount = 64;

    for (int i = t; i < FIN * HC / 4; i += 256)
        ((float4*)ws)[i] = ((const float4*)W)[i];
    const float4* xg = (const float4*)(x + (size_t)nbase * FIN);
    int nf4 = bcount * FIN / 4;
    for (int i = t; i < 64 * FIN / 4; i += 256) {
        if (i < nf4) {
            float4 v = xg[i];
            int flat = i * 4;
            int row = flat / FIN, col = flat % FIN;
            *(float4*)&xs[row * PAD + col] = v;
        }
    }
    __syncthreads();

    int cg = t & 7, np = t >> 3;
    int n0 = np * 2, n1 = n0 + 1;
    float acc0[4] = {0.f, 0.f, 0.f, 0.f};
    float acc1[4] = {0.f, 0.f, 0.f, 0.f};
#pragma unroll
    for (int k = 0; k < FIN; k += 4) {
        float4 xa = *(const float4*)&xs[n0 * PAD + k];
        float4 xb = *(const float4*)&xs[n1 * PAD + k];
        const float4* wp = (const float4*)&ws[k * HC] + cg;
        float4 w0 = wp[0], w1 = wp[8], w2 = wp[16], w3 = wp[24];
        COLS(acc0, xa)
        COLS(acc1, xb)
    }

    int hh = cg >> 2;
    float s0 = 0.f, d0 = 0.f, s1 = 0.f, d1 = 0.f;
#pragma unroll
    for (int j = 0; j < 4; ++j) {
        float av = a_src[hh * CH + (cg & 3) * 4 + j];
        float dv = a_dst[hh * CH + (cg & 3) * 4 + j];
        s0 = fmaf(acc0[j], av, s0); d0 = fmaf(acc0[j], dv, d0);
        s1 = fmaf(acc1[j], av, s1); d1 = fmaf(acc1[j], dv, d1);
    }
    s0 += __shfl_xor(s0, 1, 64); s0 += __shfl_xor(s0, 2, 64);
    d0 += __shfl_xor(d0, 1, 64); d0 += __shfl_xor(d0, 2, 64);
    s1 += __shfl_xor(s1, 1, 64); s1 += __shfl_xor(s1, 2, 64);
    d1 += __shfl_xor(d1, 1, 64); d1 += __shfl_xor(d1, 2, 64);

    if (n0 < bcount) {
        __half2 pa = __floats2half2_rn(acc0[0], acc0[1]);
        __half2 pb = __floats2half2_rn(acc0[2], acc0[3]);
        *(uint2*)&h16[(size_t)(nbase + n0) * HC + cg * 4] =
            make_uint2(*(unsigned*)&pa, *(unsigned*)&pb);
        if ((cg & 3) == 0) {
            asrc[(nbase + n0) * 2 + hh] = s0;
            adst[(nbase + n0) * 2 + hh] = d0;
        }
    }
    if (n1 < bcount) {
        __half2 pa = __floats2half2_rn(acc1[0], acc1[1]);
        __half2 pb = __floats2half2_rn(acc1[2], acc1[3]);
        *(uint2*)&h16[(size_t)(nbase + n1) * HC + cg * 4] =
            make_uint2(*(unsigned*)&pa, *(unsigned*)&pb);
        if ((cg & 3) == 0) {
            asrc[(nbase + n1) * 2 + hh] = s1;
            adst[(nbase + n1) * 2 + hh] = d1;
        }
    }
}

// ---------- fused GAT layer: 16 lanes/node, fp16 h gathers, split edge arrays ----------

#define FMA4(ACC, WGT, VEC)                                                      \
    ACC.x = fmaf(WGT, VEC.x, ACC.x); ACC.y = fmaf(WGT, VEC.y, ACC.y);            \
    ACC.z = fmaf(WGT, VEC.z, ACC.z); ACC.w = fmaf(WGT, VEC.w, ACC.w);

__device__ __forceinline__ void unpack8(uint4 hv, float4& p, float4& u) {
    float2 f0 = __half22float2(*(__half2*)&hv.x);
    float2 f1 = __half22float2(*(__half2*)&hv.y);
    float2 f2 = __half22float2(*(__half2*)&hv.z);
    float2 f3 = __half22float2(*(__half2*)&hv.w);
    p = make_float4(f0.x, f0.y, f1.x, f1.y);
    u = make_float4(f2.x, f2.y, f3.x, f3.y);
}

template <int FUSE>
__global__ __launch_bounds__(256)
void k_gat(const int* __restrict__ rowptr, const int* __restrict__ eidx,
           const __half* __restrict__ eea, const __half* __restrict__ h16,
           const float* __restrict__ asrc, const float* __restrict__ adst,
           const float* __restrict__ params, int ceoff,
           const float* __restrict__ bias, int do_relu,
           float* __restrict__ outf, __half* __restrict__ outh,
           const float* __restrict__ W2,
           const float* __restrict__ as2, const float* __restrict__ ad2,
           float* __restrict__ asrc2, float* __restrict__ adst2) {
    __shared__ float w2s[FUSE ? HC * HC : 4];
    int t = threadIdx.x;
    if (FUSE) {
        for (int i = t; i < HC * HC / 4; i += 256)
            ((float4*)w2s)[i] = ((const float4*)W2)[i];
        __syncthreads();
    }
    int tid = blockIdx.x * blockDim.x + t;
    int n = tid >> 4;
    if (n >= N_NODES) return;
    int q = tid & 15;
    int chan = q & 3, quarter = q >> 2, hh = chan >> 1;
    int st = rowptr[n], en = rowptr[n + 1];
    int len = en - st;
    int q0 = st + ((len * quarter) >> 2);
    int q1 = st + ((len * (quarter + 1)) >> 2);
    float ce = params[ceoff + hh];
    float adn = adst[n * 2 + hh];
    const uint4* h4v = (const uint4*)h16;     // one uint4 = 8 halfs = this lane's channels
    float4 A0 = make_float4(0.f, 0.f, 0.f, 0.f);
    float4 A1 = make_float4(0.f, 0.f, 0.f, 0.f);
    float ssum = 0.f;
    for (int e = q0; e < q1; e += 4) {
        int e1 = e + 1, e2 = e + 2, e3 = e + 3;
        int i1 = e1 < q1 ? e1 : q1 - 1;
        int i2 = e2 < q1 ? e2 : q1 - 1;
        int i3 = e3 < q1 ? e3 : q1 - 1;
        int r0 = eidx[e], r1 = eidx[i1], r2 = eidx[i2], r3 = eidx[i3];
        float ea0 = __half2float(eea[e]),  ea1 = __half2float(eea[i1]);
        float ea2 = __half2float(eea[i2]), ea3 = __half2float(eea[i3]);
        int s0 = r0 >> BSH, s1 = r1 >> BSH, s2 = r2 >> BSH, s3 = r3 >> BSH;
        float a0 = asrc[s0 * 2 + hh], a1 = asrc[s1 * 2 + hh];
        float a2 = asrc[s2 * 2 + hh], a3 = asrc[s3 * 2 + hh];
        uint4 hv0 = h4v[s0 * 4 + chan];
        uint4 hv1 = h4v[s1 * 4 + chan];
        uint4 hv2 = h4v[s2 * 4 + chan];
        uint4 hv3 = h4v[s3 * 4 + chan];
        float g0 = __expf(lrelu(a0 + adn + ce * ea0));
        float g1 = __expf(lrelu(a1 + adn + ce * ea1));
        float g2 = __expf(lrelu(a2 + adn + ce * ea2));
        float g3 = __expf(lrelu(a3 + adn + ce * ea3));
        g1 = (e1 < q1) ? g1 : 0.f;
        g2 = (e2 < q1) ? g2 : 0.f;
        g3 = (e3 < q1) ? g3 : 0.f;
        float4 p0, u0, p1, u1, p2, u2, p3, u3;
        unpack8(hv0, p0, u0); unpack8(hv1, p1, u1);
        unpack8(hv2, p2, u2); unpack8(hv3, p3, u3);
        FMA4(A0, g0, p0) FMA4(A1, g0, u0) ssum += g0;
        FMA4(A0, g1, p1) FMA4(A1, g1, u1) ssum += g1;
        FMA4(A0, g2, p2) FMA4(A1, g2, u2) ssum += g2;
        FMA4(A0, g3, p3) FMA4(A1, g3, u3) ssum += g3;
    }
    if (quarter == 0) {
        // self-loop (eattr = mean) counted once, in quarter 0
        float gself = __expf(lrelu(asrc[n * 2 + hh] + adn + ce * params[1]));
        float4 psf, usf;
        unpack8(h4v[n * 4 + chan], psf, usf);
        FMA4(A0, gself, psf) FMA4(A1, gself, usf)
        ssum += gself;
    }
    // merge the four edge-quarters: partner lanes tid^4 then tid^8 (same wave)
    A0.x += __shfl_xor(A0.x, 4, 64); A0.y += __shfl_xor(A0.y, 4, 64);
    A0.z += __shfl_xor(A0.z, 4, 64); A0.w += __shfl_xor(A0.w, 4, 64);
    A1.x += __shfl_xor(A1.x, 4, 64); A1.y += __shfl_xor(A1.y, 4, 64);
    A1.z += __shfl_xor(A1.z, 4, 64); A1.w += __shfl_xor(A1.w, 4, 64);
    ssum += __shfl_xor(ssum, 4, 64);
    A0.x += __shfl_xor(A0.x, 8, 64); A0.y += __shfl_xor(A0.y, 8, 64);
    A0.z += __shfl_xor(A0.z, 8, 64); A0.w += __shfl_xor(A0.w, 8, 64);
    A1.x += __shfl_xor(A1.x, 8, 64); A1.y += __shfl_xor(A1.y, 8, 64);
    A1.z += __shfl_xor(A1.z, 8, 64); A1.w += __shfl_xor(A1.w, 8, 64);
    ssum += __shfl_xor(ssum, 8, 64);
    if (quarter != 0) return;
    float inv = 1.f / (ssum + 1e-16f);
    int b4 = chan * 2;
    float4 bv0 = ((const float4*)bias)[b4], bv1 = ((const float4*)bias)[b4 + 1];
    float4 v0 = make_float4(A0.x * inv + bv0.x, A0.y * inv + bv0.y,
                            A0.z * inv + bv0.z, A0.w * inv + bv0.w);
    float4 v1 = make_float4(A1.x * inv + bv1.x, A1.y * inv + bv1.y,
                            A1.z * inv + bv1.z, A1.w * inv + bv1.w);
    if (do_relu) {
        v0.x = fmaxf(v0.x, 0.f); v0.y = fmaxf(v0.y, 0.f);
        v0.z = fmaxf(v0.z, 0.f); v0.w = fmaxf(v0.w, 0.f);
        v1.x = fmaxf(v1.x, 0.f); v1.y = fmaxf(v1.y, 0.f);
        v1.z = fmaxf(v1.z, 0.f); v1.w = fmaxf(v1.w, 0.f);
    }
    if (!FUSE) {
        ((float4*)outf)[n * 8 + b4] = v0;
        ((float4*)outf)[n * 8 + b4 + 1] = v1;
        return;
    }
    // ---- fused layer-2 linear (fp32): h2 = v @ W2; chan lanes hold full row ----
    int lane = t & 63;
    int bse = lane & 48;                  // node-group lane base (quarter-0 chan lanes)
    float h2[8] = {0.f, 0.f, 0.f, 0.f, 0.f, 0.f, 0.f, 0.f};
#pragma unroll
    for (int cc = 0; cc < 4; ++cc) {
        int sl = bse | cc;
        float vv[8];
        vv[0] = __shfl(v0.x, sl, 64); vv[1] = __shfl(v0.y, sl, 64);
        vv[2] = __shfl(v0.z, sl, 64); vv[3] = __shfl(v0.w, sl, 64);
        vv[4] = __shfl(v1.x, sl, 64); vv[5] = __shfl(v1.y, sl, 64);
        vv[6] = __shfl(v1.z, sl, 64); vv[7] = __shfl(v1.w, sl, 64);
#pragma unroll
        for (int m = 0; m < 8; ++m) {      // k ascending (== k_linear order)
            const float* wrow = &w2s[(cc * 8 + m) * HC + chan * 8];
            float4 wa = *(const float4*)&wrow[0];
            float4 wb = *(const float4*)&wrow[4];
            h2[0] = fmaf(vv[m], wa.x, h2[0]); h2[1] = fmaf(vv[m], wa.y, h2[1]);
            h2[2] = fmaf(vv[m], wa.z, h2[2]); h2[3] = fmaf(vv[m], wa.w, h2[3]);
            h2[4] = fmaf(vv[m], wb.x, h2[4]); h2[5] = fmaf(vv[m], wb.y, h2[5]);
            h2[6] = fmaf(vv[m], wb.z, h2[6]); h2[7] = fmaf(vv[m], wb.w, h2[7]);
        }
    }
    __half2 q0h = __floats2half2_rn(h2[0], h2[1]);
    __half2 q1h = __floats2half2_rn(h2[2], h2[3]);
    __half2 q2h = __floats2half2_rn(h2[4], h2[5]);
    __half2 q3h = __floats2half2_rn(h2[6], h2[7]);
    *(uint4*)&outh[(size_t)n * HC + chan * 8] =
        make_uint4(*(unsigned*)&q0h, *(unsigned*)&q1h,
                   *(unsigned*)&q2h, *(unsigned*)&q3h);
    float s2 = 0.f, d2 = 0.f;
#pragma unroll
    for (int j = 0; j < 8; ++j) {
        s2 = fmaf(h2[j], as2[chan * 8 + j], s2);
        d2 = fmaf(h2[j], ad2[chan * 8 + j], d2);
    }
    s2 += __shfl_xor(s2, 1, 64);           // chan0+1 = head0, chan2+3 = head1
    d2 += __shfl_xor(d2, 1, 64);
    if ((chan & 1) == 0) {
        asrc2[n * 2 + (chan >> 1)] = s2;
        adst2[n * 2 + (chan >> 1)] = d2;
    }
}

// ---------- pooling stage 1: streaming per-graph partial sums ----------

__global__ __launch_bounds__(1024)
void k_pool1(const float* __restrict__ feat, const int* __restrict__ batch,
             float* __restrict__ gsums) {
    __shared__ float gsum[GSPAN][32];
    int t = threadIdx.x;
    int c = t & 31, r = t >> 5;     // r in 0..31, 16 nodes each
    int base = blockIdx.x * NPB;
    if (t < GSPAN * 32) ((float*)gsum)[t] = 0.f;
    __syncthreads();
    int g0 = batch[base];
    float acc = 0.f;
    int gprev = -1;
    for (int i = 0; i < NPB / 32; ++i) {
        int n = base + r * (NPB / 32) + i;
        if (n >= N_NODES) break;
        int g = batch[n] - g0;
        if (g != gprev) {
            if (gprev >= 0) {
                if (gprev < GSPAN) atomicAdd(&gsum[gprev][c], acc);
                else unsafeAtomicAdd(&gsums[(g0 + gprev) * 32 + c], acc);
            }
            acc = 0.f;
            gprev = g;
        }
        acc += feat[(size_t)n * HC + c];
    }
    if (gprev >= 0) {
        if (gprev < GSPAN) atomicAdd(&gsum[gprev][c], acc);
        else unsafeAtomicAdd(&gsums[(g0 + gprev) * 32 + c], acc);
    }
    __syncthreads();
    if (t < GSPAN * 32) {
        int gi = t >> 5, cc = t & 31;
        float v = gsum[gi][cc];
        if (v != 0.f && g0 + gi < NGRAPH)
            unsafeAtomicAdd(&gsums[(g0 + gi) * 32 + cc], v);
    }
}

// ---------- pooling stage 2: mean + MLP head (tiny) ----------

__global__ void k_mlp(const float* __restrict__ gsums, const int* __restrict__ batch,
                      const float* __restrict__ Wf1, const float* __restrict__ bf1,
                      const float* __restrict__ Wf2, const float* __restrict__ bf2,
                      float* __restrict__ out) {
    int g = blockIdx.x;
    __shared__ int sse[2];
    __shared__ float emb[32];
    __shared__ float hid[32];
    if (threadIdx.x < 2) {
        int target = g + (int)threadIdx.x;
        int lo = 0, hi = N_NODES;
        while (lo < hi) {
            int mid = (lo + hi) >> 1;
            if (batch[mid] < target) lo = mid + 1; else hi = mid;
        }
        sse[threadIdx.x] = lo;
    }
    __syncthreads();
    int cnt = sse[1] - sse[0];
    if (threadIdx.x < 32)
        emb[threadIdx.x] = gsums[g * 32 + threadIdx.x] / (float)(cnt > 0 ? cnt : 1);
    __syncthreads();
    if (threadIdx.x < 32) {
        int j = threadIdx.x;
        float a = bf1[j];
        for (int k = 0; k < 32; ++k) a = fmaf(emb[k], Wf1[k * 32 + j], a);
        hid[j] = fmaxf(a, 0.f);
    }
    __syncthreads();
    if (threadIdx.x < 2) {
        int j = threadIdx.x;
        float o = bf2[j];
        for (int k = 0; k < 32; ++k) o = fmaf(hid[k], Wf2[k * 2 + j], o);
        out[g * 2 + j] = o;
    }
}

extern "C" void kernel_launch(void* const* d_in, const int* in_sizes, int n_in,
                              void* d_out, int out_size, void* d_ws, size_t ws_size,
                              hipStream_t stream) {
    const float* x   = (const float*)d_in[0];
    const int*   ei  = (const int*)d_in[1];
    const float* ea  = (const float*)d_in[2];
    const int* batch = (const int*)d_in[3];
    const float* W1  = (const float*)d_in[4];
    const float* as1 = (const float*)d_in[5];
    const float* ad1 = (const float*)d_in[6];
    const float* We1 = (const float*)d_in[7];
    const float* ae1 = (const float*)d_in[8];
    const float* b1  = (const float*)d_in[9];
    const float* W2  = (const float*)d_in[10];
    const float* as2 = (const float*)d_in[11];
    const float* ad2 = (const float*)d_in[12];
    const float* We2 = (const float*)d_in[13];
    const float* ae2 = (const float*)d_in[14];
    const float* b2  = (const float*)d_in[15];
    const float* Wf1 = (const float*)d_in[16];
    const float* bf1 = (const float*)d_in[17];
    const float* Wf2 = (const float*)d_in[18];
    const float* bf2 = (const float*)d_in[19];
    float* out = (float*)d_out;
    (void)in_sizes; (void)n_in; (void)out_size; (void)ws_size;

    const int* srcp = ei;
    const int* dstp = ei + N_EDGES;

    char* wsb = (char*)d_ws;
    size_t off = 0;
    auto alloc = [&](size_t bytes) -> char* {
        char* p = wsb + off;
        off = (off + bytes + 255) & ~(size_t)255;
        return p;
    };
    float* params = (float*)alloc(64);
    // region A: sidx (NB2*CAP*4 = 14.4 MB); reused after k_scatter as fp32 feat buf
    char* regA = alloc((size_t)NB2 * CAP * 4 + 4096);
    int*   sidx   = (int*)regA;
    float* feat   = (float*)regA;
    __half* sea   = (__half*)alloc((size_t)NB2 * CAP * 2);
    int*   eidx   = (int*)alloc((size_t)N_EDGES * 4);
    __half* eea   = (__half*)alloc((size_t)N_EDGES * 2);
    __half* h16a  = (__half*)alloc((size_t)N_NODES * HC * 2);
    __half* h16b  = (__half*)alloc((size_t)N_NODES * HC * 2);
    float* asrc   = (float*)alloc((size_t)N_NODES * 2 * 4);
    float* adst   = (float*)alloc((size_t)N_NODES * 2 * 4);
    float* asrc2  = (float*)alloc((size_t)N_NODES * 2 * 4);
    float* adst2  = (float*)alloc((size_t)N_NODES * 2 * 4);
    int*   gstart = (int*)alloc((size_t)(NB2 + 1) * 4);
    int*   gcur   = (int*)alloc((size_t)NB2 * GPAD * 4);
    int*   rowptr = (int*)alloc((size_t)(N_NODES + 1) * 4);
    float* gsums  = (float*)alloc((size_t)NGRAPH * HC * 4);

    const int nBlkB = (N_EDGES + EPB - 1) / EPB;                // 782
    const int nBlkL = (N_NODES + 63) / 64;                      // 1563
    const int nBlkG = (N_NODES * 16 + 255) / 256;               // 6250
    const int nBlkP = (N_NODES + NPB - 1) / NPB;                // 196

    // fixed-capacity bucket sort (no pre-histogram pass)
    k_init<<<1, 1024, 0, stream>>>(gcur, params, gsums);
    k_bucket<<<nBlkB, BTHR, 0, stream>>>(srcp, dstp, ea, gcur, sidx, sea, params);
    k_setup<<<1, 256, 0, stream>>>(We1, ae1, We2, ae2, params, gcur, gstart, rowptr);
    k_scatter<<<NB2, 1024, 0, stream>>>(sidx, sea, gcur, gstart, rowptr, eidx, eea);

    // ----- layer 1 (+ fused layer-2 linear in epilogue, fp16 tables) -----
    k_linear<F_IN><<<nBlkL, 256, 0, stream>>>(x, W1, as1, ad1, h16a, asrc, adst);
    k_gat<1><<<nBlkG, 256, 0, stream>>>(rowptr, eidx, eea, h16a, asrc, adst, params, 2, b1, 1,
                                        nullptr, h16b, W2, as2, ad2, asrc2, adst2);

    // ----- layer 2 (reads fp16 h2; writes fp32 features into regA) -----
    k_gat<0><<<nBlkG, 256, 0, stream>>>(rowptr, eidx, eea, h16b, asrc2, adst2, params, 4, b2, 0,
                                        feat, nullptr, W2, as2, ad2, asrc2, adst2);

    // ----- pool (streaming partials) + MLP head -----
    k_pool1<<<nBlkP, 1024, 0, stream>>>(feat, batch, gsums);
    k_mlp<<<NGRAPH, 64, 0, stream>>>(gsums, batch, Wf1, bf1, Wf2, bf2, out);
}